// Round 2
// baseline (632.274 us; speedup 1.0000x reference)
//
#include <hip/hip_runtime.h>
#include <hip/hip_bf16.h>
#include <math.h>

#define B_ 4
#define S_ 2048
#define C_ 1024
#define H_ 16
#define D_ 64
#define M_ (B_*S_)      // 8192
#define NQKV (3*C_)     // 3072
#define KDIM C_         // 1024

typedef float f32x4 __attribute__((ext_vector_type(4)));
typedef short bf16x8 __attribute__((ext_vector_type(8)));

static __device__ __forceinline__ ushort f2bf(float f){
    union { float f; unsigned int i; } v; v.f = f;
    unsigned int r = v.i + 0x7fffu + ((v.i >> 16) & 1u);
    return (ushort)(r >> 16);
}

// ---------------- convert x -> bf16 ----------------
__global__ void k_conv(const float* __restrict__ in, ushort* __restrict__ out, int n4){
    int i = blockIdx.x*blockDim.x + threadIdx.x;
    if (i < n4){
        float4 v = *(const float4*)(in + i*4);
        ushort4 o;
        o.x = f2bf(v.x); o.y = f2bf(v.y); o.z = f2bf(v.z); o.w = f2bf(v.w);
        *(ushort4*)(out + i*4) = o;
    }
}

// ---------------- transpose+convert W [R][Ccol] -> [Ccol][R] bf16 ----------------
__global__ void k_transpose(const float* __restrict__ in, ushort* __restrict__ out,
                            int R, int Ccol){
    __shared__ float tile[32][33];
    int c0 = blockIdx.x*32, r0 = blockIdx.y*32;
    int tx = threadIdx.x, ty = threadIdx.y;   // block (32,8)
    for (int j = ty; j < 32; j += 8)
        tile[j][tx] = in[(r0 + j)*Ccol + c0 + tx];
    __syncthreads();
    for (int j = ty; j < 32; j += 8)
        out[(size_t)(c0 + tx)*R + r0 + j] = f2bf(tile[j][tx]);
}

// ---------------- rope cos/sin tables [S][64] ----------------
__global__ void k_rope_tab(float* __restrict__ cosT, float* __restrict__ sinT){
    int t = blockIdx.x*blockDim.x + threadIdx.x;
    if (t >= S_*D_) return;
    int pos = t >> 6, j = t & 63;
    float invf = powf(10000.0f, -(float)(j & 31) / 32.0f);
    float ang = (float)pos * invf;
    cosT[t] = cosf(ang);
    sinT[t] = sinf(ang);
}

// ---------------- QKV GEMM + bias + RoPE + scatter; V goes out transposed ----------------
__launch_bounds__(256)
__global__ void k_qkv(const ushort* __restrict__ xb, const ushort* __restrict__ wt,
                      const float* __restrict__ bqkv,
                      const float* __restrict__ cosT, const float* __restrict__ sinT,
                      ushort* __restrict__ qb, ushort* __restrict__ kb, ushort* __restrict__ vT){
    __shared__ __align__(16) ushort As[64][32];
    __shared__ __align__(16) ushort Bs[64][32];
    int M0 = blockIdx.y*64, N0 = blockIdx.x*64;
    int tid = threadIdx.x;
    int wid = tid >> 6, lane = tid & 63;
    int wm = wid >> 1, wn = wid & 1;
    int lrow = lane & 15, lk = lane >> 4;

    f32x4 acc[2][2] = {};
    int r = tid >> 2, cg = tid & 3;
    for (int k0 = 0; k0 < KDIM; k0 += 32){
        *(int4*)(&As[r][cg*8]) = *(const int4*)(&xb[(M0 + r)*KDIM + k0 + cg*8]);
        *(int4*)(&Bs[r][cg*8]) = *(const int4*)(&wt[(N0 + r)*KDIM + k0 + cg*8]);
        __syncthreads();
        bf16x8 a[2], b[2];
#pragma unroll
        for (int mi = 0; mi < 2; mi++) a[mi] = *(const bf16x8*)(&As[wm*32 + mi*16 + lrow][lk*8]);
#pragma unroll
        for (int ni = 0; ni < 2; ni++) b[ni] = *(const bf16x8*)(&Bs[wn*32 + ni*16 + lrow][lk*8]);
#pragma unroll
        for (int mi = 0; mi < 2; mi++)
#pragma unroll
            for (int ni = 0; ni < 2; ni++)
                acc[mi][ni] = __builtin_amdgcn_mfma_f32_16x16x32_bf16(a[mi], b[ni], acc[mi][ni], 0, 0, 0);
        __syncthreads();
    }
#pragma unroll
    for (int mi = 0; mi < 2; mi++)
#pragma unroll
    for (int ni = 0; ni < 2; ni++){
        int gn = N0 + wn*32 + ni*16 + lrow;
        float bias = bqkv[gn];
        int which = gn >> 10;       // 0=q 1=k 2=v (uniform per wave subtile)
        int cn = gn & 1023;
        int h = cn >> 6, d = cn & 63;
        if (which == 2){
            int gm0 = M0 + wm*32 + mi*16 + lk*4;
            int bb = gm0 >> 11, pos0 = gm0 & 2047;
            ushort4 o = { f2bf(acc[mi][ni][0] + bias), f2bf(acc[mi][ni][1] + bias),
                          f2bf(acc[mi][ni][2] + bias), f2bf(acc[mi][ni][3] + bias) };
            *(ushort4*)(&vT[(((size_t)(bb*H_ + h))*D_ + d)*S_ + pos0]) = o;
        } else {
#pragma unroll
            for (int rr = 0; rr < 4; rr++){
                int gm = M0 + wm*32 + mi*16 + lk*4 + rr;
                float val = acc[mi][ni][rr] + bias;
                float rot = __shfl_xor(val, 1);       // partner col (d^1), bias included
                int bb = gm >> 11, pos = gm & 2047;
                int out_idx = ((((bb*H_ + h)*S_) + pos))*D_ + d;
                float c = cosT[pos*64 + d], s = sinT[pos*64 + d];
                float o = val*c + ((d & 1) ? rot : -rot)*s;
                ((which == 0) ? qb : kb)[out_idx] = f2bf(o);
            }
        }
    }
}

// ---------------- causal flash attention (swapped QK^T), [B,H,S,D] -> [B,S,C] bf16 ----------------
__launch_bounds__(256)
__global__ void k_attn(const ushort* __restrict__ qb, const ushort* __restrict__ kb,
                       const ushort* __restrict__ vT, ushort* __restrict__ ob){
    __shared__ __align__(16) ushort ptile[4][16][40];   // pad 40 -> 80B rows (16B-aligned, 2-way banks)
    int bh = blockIdx.y;
    int bb = bh >> 4, h = bh & 15;
    int tid = threadIdx.x, wid = tid >> 6, lane = tid & 63;
    int lrow = lane & 15, lk = lane >> 4;
    const ushort* qp = qb + (size_t)bh*S_*D_;
    const ushort* kp = kb + (size_t)bh*S_*D_;
    const ushort* vp = vT + (size_t)bh*D_*S_;
    int qbase = blockIdx.x*64 + wid*16;
    int qrow = qbase + lrow;        // this lane's q-row (col of swapped score)

    bf16x8 fq[2];
#pragma unroll
    for (int kt = 0; kt < 2; kt++)
        fq[kt] = *(const bf16x8*)(&qp[(qbase + lrow)*D_ + kt*32 + lk*8]);

    f32x4 acc[4] = {};              // [d][q] layout: col=q=lrow, row d = nt*16 + lk*4 + r
    float m = -1e30f, l = 0.0f;

    for (int j0 = 0; j0 < qbase + 16; j0 += 32){
        bf16x8 fk[2][2];
#pragma unroll
        for (int s2 = 0; s2 < 2; s2++)
#pragma unroll
            for (int kt = 0; kt < 2; kt++)
                fk[s2][kt] = *(const bf16x8*)(&kp[(j0 + s2*16 + lrow)*D_ + kt*32 + lk*8]);
        // scores^T: S[key = j0 + s2*16 + lk*4 + r][q = qrow]
        f32x4 sc[2];
#pragma unroll
        for (int s2 = 0; s2 < 2; s2++){
            f32x4 z = {};
            z = __builtin_amdgcn_mfma_f32_16x16x32_bf16(fk[s2][0], fq[0], z, 0, 0, 0);
            z = __builtin_amdgcn_mfma_f32_16x16x32_bf16(fk[s2][1], fq[1], z, 0, 0, 0);
            sc[s2] = z;
        }
        float p[2][4];
        float tmax = -1e30f;
#pragma unroll
        for (int s2 = 0; s2 < 2; s2++)
#pragma unroll
            for (int r = 0; r < 4; r++){
                int key = j0 + s2*16 + lk*4 + r;
                float v = sc[s2][r]*0.125f;
                if (key > qrow) v = -1e30f;
                p[s2][r] = v;
                tmax = fmaxf(tmax, v);
            }
        tmax = fmaxf(tmax, __shfl_xor(tmax, 16));
        tmax = fmaxf(tmax, __shfl_xor(tmax, 32));
        float newm = fmaxf(m, tmax);
        float resc = __expf(m - newm);
        float rsum = 0.0f;
#pragma unroll
        for (int s2 = 0; s2 < 2; s2++)
#pragma unroll
            for (int r = 0; r < 4; r++){
                float e = __expf(p[s2][r] - newm);
                p[s2][r] = e;
                rsum += e;
            }
        rsum += __shfl_xor(rsum, 16);
        rsum += __shfl_xor(rsum, 32);
        l = l*resc + rsum;
        m = newm;
#pragma unroll
        for (int nt = 0; nt < 4; nt++)
#pragma unroll
            for (int r = 0; r < 4; r++) acc[nt][r] *= resc;
        // P^T (lane: q=lrow, keys s2*16+lk*4+{0..3}) -> LDS as P[q][key]
#pragma unroll
        for (int s2 = 0; s2 < 2; s2++)
#pragma unroll
            for (int i = 0; i < 2; i++){
                unsigned int w = (unsigned int)f2bf(p[s2][2*i]) |
                                 ((unsigned int)f2bf(p[s2][2*i+1]) << 16);
                *(unsigned int*)(&ptile[wid][lrow][s2*16 + lk*4 + 2*i]) = w;
            }
        bf16x8 fp = *(const bf16x8*)(&ptile[wid][lrow][lk*8]);   // B-frag: P[q=lrow][key=lk*8+e]
#pragma unroll
        for (int nt = 0; nt < 4; nt++){
            bf16x8 fv = *(const bf16x8*)(&vp[(nt*16 + lrow)*S_ + j0 + lk*8]); // A-frag: V^T[d][key]
            acc[nt] = __builtin_amdgcn_mfma_f32_16x16x32_bf16(fv, fp, acc[nt], 0, 0, 0);
        }
    }
    float rl = 1.0f / l;
#pragma unroll
    for (int nt = 0; nt < 4; nt++){
        ushort4 o = { f2bf(acc[nt][0]*rl), f2bf(acc[nt][1]*rl),
                      f2bf(acc[nt][2]*rl), f2bf(acc[nt][3]*rl) };
        *(ushort4*)(&ob[((size_t)(bb*S_ + qrow))*C_ + h*D_ + nt*16 + lk*4]) = o;
    }
}

// ---------------- proj GEMM + bias -> fp32 out ----------------
__launch_bounds__(256)
__global__ void k_proj(const ushort* __restrict__ ab, const ushort* __restrict__ wt,
                       const float* __restrict__ bias, float* __restrict__ out){
    __shared__ __align__(16) ushort As[64][32];
    __shared__ __align__(16) ushort Bs[64][32];
    int M0 = blockIdx.y*64, N0 = blockIdx.x*64;
    int tid = threadIdx.x;
    int wid = tid >> 6, lane = tid & 63;
    int wm = wid >> 1, wn = wid & 1;
    int lrow = lane & 15, lk = lane >> 4;

    f32x4 acc[2][2] = {};
    int r = tid >> 2, cg = tid & 3;
    for (int k0 = 0; k0 < KDIM; k0 += 32){
        *(int4*)(&As[r][cg*8]) = *(const int4*)(&ab[(M0 + r)*KDIM + k0 + cg*8]);
        *(int4*)(&Bs[r][cg*8]) = *(const int4*)(&wt[(N0 + r)*KDIM + k0 + cg*8]);
        __syncthreads();
        bf16x8 a[2], b[2];
#pragma unroll
        for (int mi = 0; mi < 2; mi++) a[mi] = *(const bf16x8*)(&As[wm*32 + mi*16 + lrow][lk*8]);
#pragma unroll
        for (int ni = 0; ni < 2; ni++) b[ni] = *(const bf16x8*)(&Bs[wn*32 + ni*16 + lrow][lk*8]);
#pragma unroll
        for (int mi = 0; mi < 2; mi++)
#pragma unroll
            for (int ni = 0; ni < 2; ni++)
                acc[mi][ni] = __builtin_amdgcn_mfma_f32_16x16x32_bf16(a[mi], b[ni], acc[mi][ni], 0, 0, 0);
        __syncthreads();
    }
#pragma unroll
    for (int mi = 0; mi < 2; mi++)
#pragma unroll
    for (int ni = 0; ni < 2; ni++){
        int gn = N0 + wn*32 + ni*16 + lrow;
        float bv = bias[gn];
#pragma unroll
        for (int rr = 0; rr < 4; rr++){
            int gm = M0 + wm*32 + mi*16 + lk*4 + rr;
            out[gm*C_ + gn] = acc[mi][ni][rr] + bv;
        }
    }
}

extern "C" void kernel_launch(void* const* d_in, const int* in_sizes, int n_in,
                              void* d_out, int out_size, void* d_ws, size_t ws_size,
                              hipStream_t stream) {
    const float* x     = (const float*)d_in[0];
    const float* Wqkv  = (const float*)d_in[1];
    const float* bqkv  = (const float*)d_in[2];
    const float* Wproj = (const float*)d_in[3];
    const float* bproj = (const float*)d_in[4];
    float* out = (float*)d_out;

    char* ws = (char*)d_ws;
    ushort* xb   = (ushort*)(ws);                                  // 16 MB
    ushort* wqt  = (ushort*)(ws + (16u<<20));                      // 6 MB
    ushort* wpt  = (ushort*)(ws + (22u<<20));                      // 2 MB
    float*  cosT = (float*) (ws + (24u<<20));                      // 0.5 MB
    float*  sinT = (float*) (ws + (24u<<20) + (512u<<10));         // 0.5 MB
    ushort* qbuf = (ushort*)(ws + (25u<<20));                      // 16 MB
    ushort* kbuf = (ushort*)(ws + (41u<<20));                      // 16 MB
    ushort* vbuf = (ushort*)(ws + (57u<<20));                      // 16 MB  (transposed [bh][D][S])
    ushort* obuf = (ushort*)(ws + (73u<<20));                      // 16 MB

    k_conv<<<(M_*KDIM/4 + 255)/256, 256, 0, stream>>>(x, xb, M_*KDIM/4);
    dim3 tb(32, 8);
    k_transpose<<<dim3(NQKV/32, KDIM/32), tb, 0, stream>>>(Wqkv, wqt, KDIM, NQKV);
    k_transpose<<<dim3(C_/32, KDIM/32), tb, 0, stream>>>(Wproj, wpt, KDIM, C_);
    k_rope_tab<<<(S_*D_ + 255)/256, 256, 0, stream>>>(cosT, sinT);

    k_qkv<<<dim3(NQKV/64, M_/64), 256, 0, stream>>>(xb, wqt, bqkv, cosT, sinT, qbuf, kbuf, vbuf);
    k_attn<<<dim3(S_/64, B_*H_), 256, 0, stream>>>(qbuf, kbuf, vbuf, obuf);
    k_proj<<<dim3(C_/64, M_/64), 256, 0, stream>>>(obuf, wpt, bproj, out);
}

// Round 3
// 290.656 us; speedup vs baseline: 2.1753x; 2.1753x over previous
//
#include <hip/hip_runtime.h>
#include <hip/hip_bf16.h>
#include <math.h>

#define B_ 4
#define S_ 2048
#define C_ 1024
#define H_ 16
#define D_ 64
#define M_ (B_*S_)      // 8192
#define NQKV (3*C_)     // 3072
#define KDIM C_         // 1024

typedef float f32x4 __attribute__((ext_vector_type(4)));
typedef short bf16x8 __attribute__((ext_vector_type(8)));

static __device__ __forceinline__ ushort f2bf(float f){
    union { float f; unsigned int i; } v; v.f = f;
    unsigned int r = v.i + 0x7fffu + ((v.i >> 16) & 1u);
    return (ushort)(r >> 16);
}

// ---------------- convert x -> bf16 ----------------
__global__ void k_conv(const float* __restrict__ in, ushort* __restrict__ out, int n4){
    int i = blockIdx.x*blockDim.x + threadIdx.x;
    if (i < n4){
        float4 v = *(const float4*)(in + i*4);
        ushort4 o;
        o.x = f2bf(v.x); o.y = f2bf(v.y); o.z = f2bf(v.z); o.w = f2bf(v.w);
        *(ushort4*)(out + i*4) = o;
    }
}

// ---------------- transpose+convert W [R][Ccol] -> [Ccol][R] bf16 ----------------
__global__ void k_transpose(const float* __restrict__ in, ushort* __restrict__ out,
                            int R, int Ccol){
    __shared__ float tile[32][33];
    int c0 = blockIdx.x*32, r0 = blockIdx.y*32;
    int tx = threadIdx.x, ty = threadIdx.y;   // block (32,8)
    for (int j = ty; j < 32; j += 8)
        tile[j][tx] = in[(r0 + j)*Ccol + c0 + tx];
    __syncthreads();
    for (int j = ty; j < 32; j += 8)
        out[(size_t)(c0 + tx)*R + r0 + j] = f2bf(tile[j][tx]);
}

// ---------------- rope cos/sin tables [S][64] ----------------
__global__ void k_rope_tab(float* __restrict__ cosT, float* __restrict__ sinT){
    int t = blockIdx.x*blockDim.x + threadIdx.x;
    if (t >= S_*D_) return;
    int pos = t >> 6, j = t & 63;
    float invf = powf(10000.0f, -(float)(j & 31) / 32.0f);
    float ang = (float)pos * invf;
    cosT[t] = cosf(ang);
    sinT[t] = sinf(ang);
}

// ---------------- QKV GEMM + bias + RoPE + scatter; V goes out transposed ----------------
__launch_bounds__(256)
__global__ void k_qkv(const ushort* __restrict__ xb, const ushort* __restrict__ wt,
                      const float* __restrict__ bqkv,
                      const float* __restrict__ cosT, const float* __restrict__ sinT,
                      ushort* __restrict__ qb, ushort* __restrict__ kb, ushort* __restrict__ vT){
    __shared__ __align__(16) ushort As[64][32];
    __shared__ __align__(16) ushort Bs[64][32];
    int M0 = blockIdx.y*64, N0 = blockIdx.x*64;
    int tid = threadIdx.x;
    int wid = tid >> 6, lane = tid & 63;
    int wm = wid >> 1, wn = wid & 1;
    int lrow = lane & 15, lk = lane >> 4;

    f32x4 acc[2][2] = {};
    int r = tid >> 2, cg = tid & 3;
    for (int k0 = 0; k0 < KDIM; k0 += 32){
        *(int4*)(&As[r][cg*8]) = *(const int4*)(&xb[(M0 + r)*KDIM + k0 + cg*8]);
        *(int4*)(&Bs[r][cg*8]) = *(const int4*)(&wt[(N0 + r)*KDIM + k0 + cg*8]);
        __syncthreads();
        bf16x8 a[2], b[2];
#pragma unroll
        for (int mi = 0; mi < 2; mi++) a[mi] = *(const bf16x8*)(&As[wm*32 + mi*16 + lrow][lk*8]);
#pragma unroll
        for (int ni = 0; ni < 2; ni++) b[ni] = *(const bf16x8*)(&Bs[wn*32 + ni*16 + lrow][lk*8]);
#pragma unroll
        for (int mi = 0; mi < 2; mi++)
#pragma unroll
            for (int ni = 0; ni < 2; ni++)
                acc[mi][ni] = __builtin_amdgcn_mfma_f32_16x16x32_bf16(a[mi], b[ni], acc[mi][ni], 0, 0, 0);
        __syncthreads();
    }
#pragma unroll
    for (int mi = 0; mi < 2; mi++)
#pragma unroll
    for (int ni = 0; ni < 2; ni++){
        int gn = N0 + wn*32 + ni*16 + lrow;
        float bias = bqkv[gn];
        int which = gn >> 10;       // 0=q 1=k 2=v (uniform per wave subtile)
        int cn = gn & 1023;
        int h = cn >> 6, d = cn & 63;
        if (which == 2){
            int gm0 = M0 + wm*32 + mi*16 + lk*4;
            int bb = gm0 >> 11, pos0 = gm0 & 2047;
            ushort4 o = { f2bf(acc[mi][ni][0] + bias), f2bf(acc[mi][ni][1] + bias),
                          f2bf(acc[mi][ni][2] + bias), f2bf(acc[mi][ni][3] + bias) };
            *(ushort4*)(&vT[(((size_t)(bb*H_ + h))*D_ + d)*S_ + pos0]) = o;
        } else {
#pragma unroll
            for (int rr = 0; rr < 4; rr++){
                int gm = M0 + wm*32 + mi*16 + lk*4 + rr;
                float val = acc[mi][ni][rr] + bias;
                float rot = __shfl_xor(val, 1);       // partner col (d^1), bias included
                int bb = gm >> 11, pos = gm & 2047;
                int out_idx = ((((bb*H_ + h)*S_) + pos))*D_ + d;
                float c = cosT[pos*64 + d], s = sinT[pos*64 + d];
                float o = val*c + ((d & 1) ? rot : -rot)*s;
                ((which == 0) ? qb : kb)[out_idx] = f2bf(o);
            }
        }
    }
}

// ---------------- causal flash attention, LDS-staged KV, swapped QK^T ----------------
// grid = (bh, qtile) for CU load balance.  Block: 4 waves x 16 q-rows = 64 q-rows.
__launch_bounds__(256)
__global__ void k_attn(const ushort* __restrict__ qb, const ushort* __restrict__ kb,
                       const ushort* __restrict__ vT, ushort* __restrict__ ob){
    __shared__ __align__(16) ushort Ks[64][72];        // K[key][d], pad 72 -> uniform b128 spans
    __shared__ __align__(16) ushort Vs[64][72];        // V^T[d][key]
    __shared__ __align__(16) ushort ptile[4][16][72];  // per-wave P[q][key 0..63]
    int bh = blockIdx.x;
    int qt = blockIdx.y;
    int bb = bh >> 4, h = bh & 15;
    int tid = threadIdx.x, wid = tid >> 6, lane = tid & 63;
    int lrow = lane & 15, lk = lane >> 4;
    const ushort* qp = qb + (size_t)bh*S_*D_;
    const ushort* kp = kb + (size_t)bh*S_*D_;
    const ushort* vp = vT + (size_t)bh*D_*S_;
    int qbase = qt*64 + wid*16;
    int qrow = qbase + lrow;        // this lane's q-row (col of swapped score)

    bf16x8 fq[2];
#pragma unroll
    for (int kt = 0; kt < 2; kt++)
        fq[kt] = *(const bf16x8*)(&qp[qrow*D_ + kt*32 + lk*8]);

    f32x4 acc[4] = {};              // [d][q]: col=q=lrow, row d = nt*16 + lk*4 + r
    float m = -1e30f, l = 0.0f;

    int tr = tid >> 3;              // 0..31
    int tc = (tid & 7) * 8;         // 0..56

    for (int j0 = 0; j0 <= qt*64; j0 += 64){
        // ---- cooperative stage: K tile (rows j0..j0+63) and V^T tile (keys j0..j0+63)
        *(int4*)(&Ks[tr][tc])      = *(const int4*)(&kp[(j0 + tr)*D_ + tc]);
        *(int4*)(&Ks[tr + 32][tc]) = *(const int4*)(&kp[(j0 + tr + 32)*D_ + tc]);
        *(int4*)(&Vs[tr][tc])      = *(const int4*)(&vp[(size_t)tr*S_ + j0 + tc]);
        *(int4*)(&Vs[tr + 32][tc]) = *(const int4*)(&vp[(size_t)(tr + 32)*S_ + j0 + tc]);
        __syncthreads();

        // ---- scores^T: S[key][q], key = j0 + s2*16 + lk*4 + r, q = qrow
        float p[4][4];
        float tmax = -1e30f;
#pragma unroll
        for (int s2 = 0; s2 < 4; s2++){
            bf16x8 k0 = *(const bf16x8*)(&Ks[s2*16 + lrow][lk*8]);
            bf16x8 k1 = *(const bf16x8*)(&Ks[s2*16 + lrow][32 + lk*8]);
            f32x4 z = {};
            z = __builtin_amdgcn_mfma_f32_16x16x32_bf16(k0, fq[0], z, 0, 0, 0);
            z = __builtin_amdgcn_mfma_f32_16x16x32_bf16(k1, fq[1], z, 0, 0, 0);
#pragma unroll
            for (int r = 0; r < 4; r++){
                int key = j0 + s2*16 + lk*4 + r;
                float v = z[r]*0.125f;
                if (key > qrow) v = -1e30f;
                p[s2][r] = v;
                tmax = fmaxf(tmax, v);
            }
        }
        tmax = fmaxf(tmax, __shfl_xor(tmax, 16));
        tmax = fmaxf(tmax, __shfl_xor(tmax, 32));
        float newm = fmaxf(m, tmax);
        float resc = __expf(m - newm);
        float rsum = 0.0f;
#pragma unroll
        for (int s2 = 0; s2 < 4; s2++)
#pragma unroll
            for (int r = 0; r < 4; r++){
                float e = __expf(p[s2][r] - newm);
                p[s2][r] = e;
                rsum += e;
            }
        rsum += __shfl_xor(rsum, 16);
        rsum += __shfl_xor(rsum, 32);
        l = l*resc + rsum;
        m = newm;
#pragma unroll
        for (int nt = 0; nt < 4; nt++)
#pragma unroll
            for (int r = 0; r < 4; r++) acc[nt][r] *= resc;

        // ---- P^T (lane q=lrow holds keys s2*16+lk*4+r) -> LDS as P[q][key], b64 writes
#pragma unroll
        for (int s2 = 0; s2 < 4; s2++){
            uint2 w;
            w.x = (unsigned int)f2bf(p[s2][0]) | ((unsigned int)f2bf(p[s2][1]) << 16);
            w.y = (unsigned int)f2bf(p[s2][2]) | ((unsigned int)f2bf(p[s2][3]) << 16);
            *(uint2*)(&ptile[wid][lrow][s2*16 + lk*4]) = w;
        }
        bf16x8 fp0 = *(const bf16x8*)(&ptile[wid][lrow][lk*8]);
        bf16x8 fp1 = *(const bf16x8*)(&ptile[wid][lrow][32 + lk*8]);
#pragma unroll
        for (int nt = 0; nt < 4; nt++){
            bf16x8 fv0 = *(const bf16x8*)(&Vs[nt*16 + lrow][lk*8]);
            bf16x8 fv1 = *(const bf16x8*)(&Vs[nt*16 + lrow][32 + lk*8]);
            acc[nt] = __builtin_amdgcn_mfma_f32_16x16x32_bf16(fv0, fp0, acc[nt], 0, 0, 0);
            acc[nt] = __builtin_amdgcn_mfma_f32_16x16x32_bf16(fv1, fp1, acc[nt], 0, 0, 0);
        }
        __syncthreads();
    }
    float rl = 1.0f / l;
#pragma unroll
    for (int nt = 0; nt < 4; nt++){
        ushort4 o = { f2bf(acc[nt][0]*rl), f2bf(acc[nt][1]*rl),
                      f2bf(acc[nt][2]*rl), f2bf(acc[nt][3]*rl) };
        *(ushort4*)(&ob[((size_t)(bb*S_ + qrow))*C_ + h*D_ + nt*16 + lk*4]) = o;
    }
}

// ---------------- proj GEMM + bias -> fp32 out ----------------
__launch_bounds__(256)
__global__ void k_proj(const ushort* __restrict__ ab, const ushort* __restrict__ wt,
                       const float* __restrict__ bias, float* __restrict__ out){
    __shared__ __align__(16) ushort As[64][32];
    __shared__ __align__(16) ushort Bs[64][32];
    int M0 = blockIdx.y*64, N0 = blockIdx.x*64;
    int tid = threadIdx.x;
    int wid = tid >> 6, lane = tid & 63;
    int wm = wid >> 1, wn = wid & 1;
    int lrow = lane & 15, lk = lane >> 4;

    f32x4 acc[2][2] = {};
    int r = tid >> 2, cg = tid & 3;
    for (int k0 = 0; k0 < KDIM; k0 += 32){
        *(int4*)(&As[r][cg*8]) = *(const int4*)(&ab[(M0 + r)*KDIM + k0 + cg*8]);
        *(int4*)(&Bs[r][cg*8]) = *(const int4*)(&wt[(N0 + r)*KDIM + k0 + cg*8]);
        __syncthreads();
        bf16x8 a[2], b[2];
#pragma unroll
        for (int mi = 0; mi < 2; mi++) a[mi] = *(const bf16x8*)(&As[wm*32 + mi*16 + lrow][lk*8]);
#pragma unroll
        for (int ni = 0; ni < 2; ni++) b[ni] = *(const bf16x8*)(&Bs[wn*32 + ni*16 + lrow][lk*8]);
#pragma unroll
        for (int mi = 0; mi < 2; mi++)
#pragma unroll
            for (int ni = 0; ni < 2; ni++)
                acc[mi][ni] = __builtin_amdgcn_mfma_f32_16x16x32_bf16(a[mi], b[ni], acc[mi][ni], 0, 0, 0);
        __syncthreads();
    }
#pragma unroll
    for (int mi = 0; mi < 2; mi++)
#pragma unroll
    for (int ni = 0; ni < 2; ni++){
        int gn = N0 + wn*32 + ni*16 + lrow;
        float bv = bias[gn];
#pragma unroll
        for (int rr = 0; rr < 4; rr++){
            int gm = M0 + wm*32 + mi*16 + lk*4 + rr;
            out[gm*C_ + gn] = acc[mi][ni][rr] + bv;
        }
    }
}

extern "C" void kernel_launch(void* const* d_in, const int* in_sizes, int n_in,
                              void* d_out, int out_size, void* d_ws, size_t ws_size,
                              hipStream_t stream) {
    const float* x     = (const float*)d_in[0];
    const float* Wqkv  = (const float*)d_in[1];
    const float* bqkv  = (const float*)d_in[2];
    const float* Wproj = (const float*)d_in[3];
    const float* bproj = (const float*)d_in[4];
    float* out = (float*)d_out;

    char* ws = (char*)d_ws;
    ushort* xb   = (ushort*)(ws);                                  // 16 MB
    ushort* wqt  = (ushort*)(ws + (16u<<20));                      // 6 MB
    ushort* wpt  = (ushort*)(ws + (22u<<20));                      // 2 MB
    float*  cosT = (float*) (ws + (24u<<20));                      // 0.5 MB
    float*  sinT = (float*) (ws + (24u<<20) + (512u<<10));         // 0.5 MB
    ushort* qbuf = (ushort*)(ws + (25u<<20));                      // 16 MB
    ushort* kbuf = (ushort*)(ws + (41u<<20));                      // 16 MB
    ushort* vbuf = (ushort*)(ws + (57u<<20));                      // 16 MB  (transposed [bh][D][S])
    ushort* obuf = (ushort*)(ws + (73u<<20));                      // 16 MB

    k_conv<<<(M_*KDIM/4 + 255)/256, 256, 0, stream>>>(x, xb, M_*KDIM/4);
    dim3 tb(32, 8);
    k_transpose<<<dim3(NQKV/32, KDIM/32), tb, 0, stream>>>(Wqkv, wqt, KDIM, NQKV);
    k_transpose<<<dim3(C_/32, KDIM/32), tb, 0, stream>>>(Wproj, wpt, KDIM, C_);
    k_rope_tab<<<(S_*D_ + 255)/256, 256, 0, stream>>>(cosT, sinT);

    k_qkv<<<dim3(NQKV/64, M_/64), 256, 0, stream>>>(xb, wqt, bqkv, cosT, sinT, qbuf, kbuf, vbuf);
    k_attn<<<dim3(B_*H_, S_/64), 256, 0, stream>>>(qbuf, kbuf, vbuf, obuf);
    k_proj<<<dim3(C_/64, M_/64), 256, 0, stream>>>(obuf, wpt, bproj, out);
}

// Round 4
// 249.638 us; speedup vs baseline: 2.5328x; 1.1643x over previous
//
#include <hip/hip_runtime.h>
#include <hip/hip_bf16.h>
#include <math.h>

#define B_ 4
#define S_ 2048
#define C_ 1024
#define H_ 16
#define D_ 64
#define M_ (B_*S_)      // 8192
#define NQKV (3*C_)     // 3072
#define KDIM C_         // 1024

typedef float f32x4 __attribute__((ext_vector_type(4)));
typedef short bf16x8 __attribute__((ext_vector_type(8)));

static __device__ __forceinline__ ushort f2bf(float f){
    union { float f; unsigned int i; } v; v.f = f;
    unsigned int r = v.i + 0x7fffu + ((v.i >> 16) & 1u);
    return (ushort)(r >> 16);
}

// async global->LDS, 16B per lane; lds dest = wave-uniform base + lane*16
static __device__ __forceinline__ void gload16(const ushort* g, ushort* l){
    __builtin_amdgcn_global_load_lds((__attribute__((address_space(1))) void*)g,
                                     (__attribute__((address_space(3))) void*)l,
                                     16, 0, 0);
}

// ---------------- convert x -> bf16 ----------------
__global__ void k_conv(const float* __restrict__ in, ushort* __restrict__ out, int n4){
    int i = blockIdx.x*blockDim.x + threadIdx.x;
    if (i < n4){
        float4 v = *(const float4*)(in + i*4);
        ushort4 o;
        o.x = f2bf(v.x); o.y = f2bf(v.y); o.z = f2bf(v.z); o.w = f2bf(v.w);
        *(ushort4*)(out + i*4) = o;
    }
}

// ---------------- transpose+convert W [R][Ccol] -> [Ccol][R] bf16 ----------------
__global__ void k_transpose(const float* __restrict__ in, ushort* __restrict__ out,
                            int R, int Ccol){
    __shared__ float tile[32][33];
    int c0 = blockIdx.x*32, r0 = blockIdx.y*32;
    int tx = threadIdx.x, ty = threadIdx.y;   // block (32,8)
    for (int j = ty; j < 32; j += 8)
        tile[j][tx] = in[(r0 + j)*Ccol + c0 + tx];
    __syncthreads();
    for (int j = ty; j < 32; j += 8)
        out[(size_t)(c0 + tx)*R + r0 + j] = f2bf(tile[j][tx]);
}

// ---------------- rope cos/sin tables [S][64] ----------------
__global__ void k_rope_tab(float* __restrict__ cosT, float* __restrict__ sinT){
    int t = blockIdx.x*blockDim.x + threadIdx.x;
    if (t >= S_*D_) return;
    int pos = t >> 6, j = t & 63;
    float invf = powf(10000.0f, -(float)(j & 31) / 32.0f);
    float ang = (float)pos * invf;
    cosT[t] = cosf(ang);
    sinT[t] = sinf(ang);
}

// ---------------- QKV GEMM (128x128 tile, global_load_lds) + bias + RoPE + scatter ----------------
__launch_bounds__(256)
__global__ void k_qkv(const ushort* __restrict__ xb, const ushort* __restrict__ wt,
                      const float* __restrict__ bqkv,
                      const float* __restrict__ cosT, const float* __restrict__ sinT,
                      ushort* __restrict__ qb, ushort* __restrict__ kb, ushort* __restrict__ vT){
    __shared__ __align__(16) ushort As[128][32];
    __shared__ __align__(16) ushort Bs[128][32];
    int M0 = blockIdx.y*128, N0 = blockIdx.x*128;
    int tid = threadIdx.x;
    int wid = tid >> 6, lane = tid & 63;
    int wm = wid >> 1, wn = wid & 1;
    int lrow = lane & 15, lk = lane >> 4;

    // staging: 8 chunks of 16 rows; wave w handles chunks 2w, 2w+1
    int srow0 = wid*32      + (lane >> 2);
    int srow1 = wid*32 + 16 + (lane >> 2);
    int scol  = (lane & 3) * 8;
    const ushort* gA0 = &xb[(size_t)(M0 + srow0)*KDIM + scol];
    const ushort* gA1 = &xb[(size_t)(M0 + srow1)*KDIM + scol];
    const ushort* gB0 = &wt[(size_t)(N0 + srow0)*KDIM + scol];
    const ushort* gB1 = &wt[(size_t)(N0 + srow1)*KDIM + scol];
    ushort* lA0 = &As[wid*32][0];
    ushort* lA1 = &As[wid*32 + 16][0];
    ushort* lB0 = &Bs[wid*32][0];
    ushort* lB1 = &Bs[wid*32 + 16][0];

    f32x4 acc[4][4] = {};
    for (int k0 = 0; k0 < KDIM; k0 += 32){
        gload16(gA0 + k0, lA0);
        gload16(gA1 + k0, lA1);
        gload16(gB0 + k0, lB0);
        gload16(gB1 + k0, lB1);
        __syncthreads();
        bf16x8 a[4], b[4];
#pragma unroll
        for (int mi = 0; mi < 4; mi++) a[mi] = *(const bf16x8*)(&As[wm*64 + mi*16 + lrow][lk*8]);
#pragma unroll
        for (int ni = 0; ni < 4; ni++) b[ni] = *(const bf16x8*)(&Bs[wn*64 + ni*16 + lrow][lk*8]);
#pragma unroll
        for (int mi = 0; mi < 4; mi++)
#pragma unroll
            for (int ni = 0; ni < 4; ni++)
                acc[mi][ni] = __builtin_amdgcn_mfma_f32_16x16x32_bf16(a[mi], b[ni], acc[mi][ni], 0, 0, 0);
        __syncthreads();
    }
#pragma unroll
    for (int mi = 0; mi < 4; mi++)
#pragma unroll
    for (int ni = 0; ni < 4; ni++){
        int gn = N0 + wn*64 + ni*16 + lrow;
        float bias = bqkv[gn];
        int which = gn >> 10;       // 0=q 1=k 2=v (uniform per block: 1024 % 128 == 0)
        int cn = gn & 1023;
        int h = cn >> 6, d = cn & 63;
        int gm0 = M0 + wm*64 + mi*16 + lk*4;
        if (which == 2){
            int bb = gm0 >> 11, pos0 = gm0 & 2047;
            ushort4 o = { f2bf(acc[mi][ni][0] + bias), f2bf(acc[mi][ni][1] + bias),
                          f2bf(acc[mi][ni][2] + bias), f2bf(acc[mi][ni][3] + bias) };
            *(ushort4*)(&vT[(((size_t)(bb*H_ + h))*D_ + d)*S_ + pos0]) = o;
        } else {
#pragma unroll
            for (int rr = 0; rr < 4; rr++){
                int gm = gm0 + rr;
                float val = acc[mi][ni][rr] + bias;
                float rot = __shfl_xor(val, 1);       // partner col (d^1), bias included
                int bb = gm >> 11, pos = gm & 2047;
                int out_idx = ((((bb*H_ + h)*S_) + pos))*D_ + d;
                float c = cosT[pos*64 + d], s = sinT[pos*64 + d];
                float o = val*c + ((d & 1) ? rot : -rot)*s;
                ((which == 0) ? qb : kb)[out_idx] = f2bf(o);
            }
        }
    }
}

// ---------------- causal flash attention, LDS-staged KV, swapped QK^T ----------------
// grid = (bh, qtile) for CU load balance.  Block: 4 waves x 16 q-rows = 64 q-rows.
__launch_bounds__(256)
__global__ void k_attn(const ushort* __restrict__ qb, const ushort* __restrict__ kb,
                       const ushort* __restrict__ vT, ushort* __restrict__ ob){
    __shared__ __align__(16) ushort Ks[64][72];        // K[key][d], pad 72 -> uniform b128 spans
    __shared__ __align__(16) ushort Vs[64][72];        // V^T[d][key]
    __shared__ __align__(16) ushort ptile[4][16][72];  // per-wave P[q][key 0..63]
    int bh = blockIdx.x;
    int qt = blockIdx.y;
    int bb = bh >> 4, h = bh & 15;
    int tid = threadIdx.x, wid = tid >> 6, lane = tid & 63;
    int lrow = lane & 15, lk = lane >> 4;
    const ushort* qp = qb + (size_t)bh*S_*D_;
    const ushort* kp = kb + (size_t)bh*S_*D_;
    const ushort* vp = vT + (size_t)bh*D_*S_;
    int qbase = qt*64 + wid*16;
    int qrow = qbase + lrow;        // this lane's q-row (col of swapped score)

    bf16x8 fq[2];
#pragma unroll
    for (int kt = 0; kt < 2; kt++)
        fq[kt] = *(const bf16x8*)(&qp[qrow*D_ + kt*32 + lk*8]);

    f32x4 acc[4] = {};              // [d][q]: col=q=lrow, row d = nt*16 + lk*4 + r
    float m = -1e30f, l = 0.0f;

    int tr = tid >> 3;              // 0..31
    int tc = (tid & 7) * 8;         // 0..56

    for (int j0 = 0; j0 <= qt*64; j0 += 64){
        // ---- cooperative stage: K tile (rows j0..j0+63) and V^T tile (keys j0..j0+63)
        *(int4*)(&Ks[tr][tc])      = *(const int4*)(&kp[(j0 + tr)*D_ + tc]);
        *(int4*)(&Ks[tr + 32][tc]) = *(const int4*)(&kp[(j0 + tr + 32)*D_ + tc]);
        *(int4*)(&Vs[tr][tc])      = *(const int4*)(&vp[(size_t)tr*S_ + j0 + tc]);
        *(int4*)(&Vs[tr + 32][tc]) = *(const int4*)(&vp[(size_t)(tr + 32)*S_ + j0 + tc]);
        __syncthreads();

        // ---- scores^T: S[key][q], key = j0 + s2*16 + lk*4 + r, q = qrow
        float p[4][4];
        float tmax = -1e30f;
#pragma unroll
        for (int s2 = 0; s2 < 4; s2++){
            bf16x8 k0 = *(const bf16x8*)(&Ks[s2*16 + lrow][lk*8]);
            bf16x8 k1 = *(const bf16x8*)(&Ks[s2*16 + lrow][32 + lk*8]);
            f32x4 z = {};
            z = __builtin_amdgcn_mfma_f32_16x16x32_bf16(k0, fq[0], z, 0, 0, 0);
            z = __builtin_amdgcn_mfma_f32_16x16x32_bf16(k1, fq[1], z, 0, 0, 0);
#pragma unroll
            for (int r = 0; r < 4; r++){
                int key = j0 + s2*16 + lk*4 + r;
                float v = z[r]*0.125f;
                if (key > qrow) v = -1e30f;
                p[s2][r] = v;
                tmax = fmaxf(tmax, v);
            }
        }
        tmax = fmaxf(tmax, __shfl_xor(tmax, 16));
        tmax = fmaxf(tmax, __shfl_xor(tmax, 32));
        float newm = fmaxf(m, tmax);
        float resc = __expf(m - newm);
        float rsum = 0.0f;
#pragma unroll
        for (int s2 = 0; s2 < 4; s2++)
#pragma unroll
            for (int r = 0; r < 4; r++){
                float e = __expf(p[s2][r] - newm);
                p[s2][r] = e;
                rsum += e;
            }
        rsum += __shfl_xor(rsum, 16);
        rsum += __shfl_xor(rsum, 32);
        l = l*resc + rsum;
        m = newm;
#pragma unroll
        for (int nt = 0; nt < 4; nt++)
#pragma unroll
            for (int r = 0; r < 4; r++) acc[nt][r] *= resc;

        // ---- P^T (lane q=lrow holds keys s2*16+lk*4+r) -> LDS as P[q][key], b64 writes
#pragma unroll
        for (int s2 = 0; s2 < 4; s2++){
            uint2 w;
            w.x = (unsigned int)f2bf(p[s2][0]) | ((unsigned int)f2bf(p[s2][1]) << 16);
            w.y = (unsigned int)f2bf(p[s2][2]) | ((unsigned int)f2bf(p[s2][3]) << 16);
            *(uint2*)(&ptile[wid][lrow][s2*16 + lk*4]) = w;
        }
        bf16x8 fp0 = *(const bf16x8*)(&ptile[wid][lrow][lk*8]);
        bf16x8 fp1 = *(const bf16x8*)(&ptile[wid][lrow][32 + lk*8]);
#pragma unroll
        for (int nt = 0; nt < 4; nt++){
            bf16x8 fv0 = *(const bf16x8*)(&Vs[nt*16 + lrow][lk*8]);
            bf16x8 fv1 = *(const bf16x8*)(&Vs[nt*16 + lrow][32 + lk*8]);
            acc[nt] = __builtin_amdgcn_mfma_f32_16x16x32_bf16(fv0, fp0, acc[nt], 0, 0, 0);
            acc[nt] = __builtin_amdgcn_mfma_f32_16x16x32_bf16(fv1, fp1, acc[nt], 0, 0, 0);
        }
        __syncthreads();
    }
    float rl = 1.0f / l;
#pragma unroll
    for (int nt = 0; nt < 4; nt++){
        ushort4 o = { f2bf(acc[nt][0]*rl), f2bf(acc[nt][1]*rl),
                      f2bf(acc[nt][2]*rl), f2bf(acc[nt][3]*rl) };
        *(ushort4*)(&ob[((size_t)(bb*S_ + qrow))*C_ + h*D_ + nt*16 + lk*4]) = o;
    }
}

// ---------------- proj GEMM (128x128 tile, global_load_lds) + bias -> fp32 out ----------------
__launch_bounds__(256)
__global__ void k_proj(const ushort* __restrict__ ab, const ushort* __restrict__ wt,
                       const float* __restrict__ bias, float* __restrict__ out){
    __shared__ __align__(16) ushort As[128][32];
    __shared__ __align__(16) ushort Bs[128][32];
    int M0 = blockIdx.y*128, N0 = blockIdx.x*128;
    int tid = threadIdx.x;
    int wid = tid >> 6, lane = tid & 63;
    int wm = wid >> 1, wn = wid & 1;
    int lrow = lane & 15, lk = lane >> 4;

    int srow0 = wid*32      + (lane >> 2);
    int srow1 = wid*32 + 16 + (lane >> 2);
    int scol  = (lane & 3) * 8;
    const ushort* gA0 = &ab[(size_t)(M0 + srow0)*KDIM + scol];
    const ushort* gA1 = &ab[(size_t)(M0 + srow1)*KDIM + scol];
    const ushort* gB0 = &wt[(size_t)(N0 + srow0)*KDIM + scol];
    const ushort* gB1 = &wt[(size_t)(N0 + srow1)*KDIM + scol];
    ushort* lA0 = &As[wid*32][0];
    ushort* lA1 = &As[wid*32 + 16][0];
    ushort* lB0 = &Bs[wid*32][0];
    ushort* lB1 = &Bs[wid*32 + 16][0];

    f32x4 acc[4][4] = {};
    for (int k0 = 0; k0 < KDIM; k0 += 32){
        gload16(gA0 + k0, lA0);
        gload16(gA1 + k0, lA1);
        gload16(gB0 + k0, lB0);
        gload16(gB1 + k0, lB1);
        __syncthreads();
        bf16x8 a[4], b[4];
#pragma unroll
        for (int mi = 0; mi < 4; mi++) a[mi] = *(const bf16x8*)(&As[wm*64 + mi*16 + lrow][lk*8]);
#pragma unroll
        for (int ni = 0; ni < 4; ni++) b[ni] = *(const bf16x8*)(&Bs[wn*64 + ni*16 + lrow][lk*8]);
#pragma unroll
        for (int mi = 0; mi < 4; mi++)
#pragma unroll
            for (int ni = 0; ni < 4; ni++)
                acc[mi][ni] = __builtin_amdgcn_mfma_f32_16x16x32_bf16(a[mi], b[ni], acc[mi][ni], 0, 0, 0);
        __syncthreads();
    }
#pragma unroll
    for (int mi = 0; mi < 4; mi++)
#pragma unroll
    for (int ni = 0; ni < 4; ni++){
        int gn = N0 + wn*64 + ni*16 + lrow;
        float bv = bias[gn];
#pragma unroll
        for (int rr = 0; rr < 4; rr++){
            int gm = M0 + wm*64 + mi*16 + lk*4 + rr;
            out[(size_t)gm*C_ + gn] = acc[mi][ni][rr] + bv;
        }
    }
}

extern "C" void kernel_launch(void* const* d_in, const int* in_sizes, int n_in,
                              void* d_out, int out_size, void* d_ws, size_t ws_size,
                              hipStream_t stream) {
    const float* x     = (const float*)d_in[0];
    const float* Wqkv  = (const float*)d_in[1];
    const float* bqkv  = (const float*)d_in[2];
    const float* Wproj = (const float*)d_in[3];
    const float* bproj = (const float*)d_in[4];
    float* out = (float*)d_out;

    char* ws = (char*)d_ws;
    ushort* xb   = (ushort*)(ws);                                  // 16 MB
    ushort* wqt  = (ushort*)(ws + (16u<<20));                      // 6 MB
    ushort* wpt  = (ushort*)(ws + (22u<<20));                      // 2 MB
    float*  cosT = (float*) (ws + (24u<<20));                      // 0.5 MB
    float*  sinT = (float*) (ws + (24u<<20) + (512u<<10));         // 0.5 MB
    ushort* qbuf = (ushort*)(ws + (25u<<20));                      // 16 MB
    ushort* kbuf = (ushort*)(ws + (41u<<20));                      // 16 MB
    ushort* vbuf = (ushort*)(ws + (57u<<20));                      // 16 MB  (transposed [bh][D][S])
    ushort* obuf = (ushort*)(ws + (73u<<20));                      // 16 MB

    k_conv<<<(M_*KDIM/4 + 255)/256, 256, 0, stream>>>(x, xb, M_*KDIM/4);
    dim3 tb(32, 8);
    k_transpose<<<dim3(NQKV/32, KDIM/32), tb, 0, stream>>>(Wqkv, wqt, KDIM, NQKV);
    k_transpose<<<dim3(C_/32, KDIM/32), tb, 0, stream>>>(Wproj, wpt, KDIM, C_);
    k_rope_tab<<<(S_*D_ + 255)/256, 256, 0, stream>>>(cosT, sinT);

    k_qkv<<<dim3(NQKV/128, M_/128), 256, 0, stream>>>(xb, wqt, bqkv, cosT, sinT, qbuf, kbuf, vbuf);
    k_attn<<<dim3(B_*H_, S_/64), 256, 0, stream>>>(qbuf, kbuf, vbuf, obuf);
    k_proj<<<dim3(C_/128, M_/128), 256, 0, stream>>>(obuf, wpt, bproj, out);
}

// Round 5
// 233.071 us; speedup vs baseline: 2.7128x; 1.0711x over previous
//
#include <hip/hip_runtime.h>
#include <hip/hip_bf16.h>
#include <math.h>

#define B_ 4
#define S_ 2048
#define C_ 1024
#define H_ 16
#define D_ 64
#define M_ (B_*S_)      // 8192
#define NQKV (3*C_)     // 3072
#define KDIM C_         // 1024

typedef float f32x4 __attribute__((ext_vector_type(4)));
typedef short bf16x8 __attribute__((ext_vector_type(8)));

static __device__ __forceinline__ ushort f2bf(float f){
    __hip_bfloat16 h = __float2bfloat16(f);
    union { __hip_bfloat16 b; ushort u; } v; v.b = h;
    return v.u;
}

// async global->LDS, 16B per lane; lds dest = wave-uniform base + lane*16
static __device__ __forceinline__ void gload16(const ushort* g, ushort* l){
    __builtin_amdgcn_global_load_lds((__attribute__((address_space(1))) void*)g,
                                     (__attribute__((address_space(3))) void*)l,
                                     16, 0, 0);
}

// ---------------- convert x -> bf16 ----------------
__global__ void k_conv(const float* __restrict__ in, ushort* __restrict__ out, int n4){
    int i = blockIdx.x*blockDim.x + threadIdx.x;
    if (i < n4){
        float4 v = *(const float4*)(in + i*4);
        ushort4 o;
        o.x = f2bf(v.x); o.y = f2bf(v.y); o.z = f2bf(v.z); o.w = f2bf(v.w);
        *(ushort4*)(out + i*4) = o;
    }
}

// ---------------- transpose+convert W [R][Ccol] -> [Ccol][R] bf16 ----------------
__global__ void k_transpose(const float* __restrict__ in, ushort* __restrict__ out,
                            int R, int Ccol){
    __shared__ float tile[32][33];
    int c0 = blockIdx.x*32, r0 = blockIdx.y*32;
    int tx = threadIdx.x, ty = threadIdx.y;   // block (32,8)
    for (int j = ty; j < 32; j += 8)
        tile[j][tx] = in[(r0 + j)*Ccol + c0 + tx];
    __syncthreads();
    for (int j = ty; j < 32; j += 8)
        out[(size_t)(c0 + tx)*R + r0 + j] = f2bf(tile[j][tx]);
}

// ---------------- rope cos/sin tables [S][64] ----------------
__global__ void k_rope_tab(float* __restrict__ cosT, float* __restrict__ sinT){
    int t = blockIdx.x*blockDim.x + threadIdx.x;
    if (t >= S_*D_) return;
    int pos = t >> 6, j = t & 63;
    float invf = powf(10000.0f, -(float)(j & 31) / 32.0f);
    float ang = (float)pos * invf;
    cosT[t] = cosf(ang);
    sinT[t] = sinf(ang);
}

// ---------------- QKV GEMM (128x128 tile, global_load_lds) + bias + RoPE + scatter ----------------
// q output is pre-scaled by 1/sqrt(D) = 0.125 so k_attn needs no per-score scale.
__launch_bounds__(256)
__global__ void k_qkv(const ushort* __restrict__ xb, const ushort* __restrict__ wt,
                      const float* __restrict__ bqkv,
                      const float* __restrict__ cosT, const float* __restrict__ sinT,
                      ushort* __restrict__ qb, ushort* __restrict__ kb, ushort* __restrict__ vT){
    __shared__ __align__(16) ushort As[128][32];
    __shared__ __align__(16) ushort Bs[128][32];
    int M0 = blockIdx.y*128, N0 = blockIdx.x*128;
    int tid = threadIdx.x;
    int wid = tid >> 6, lane = tid & 63;
    int wm = wid >> 1, wn = wid & 1;
    int lrow = lane & 15, lk = lane >> 4;

    int srow0 = wid*32      + (lane >> 2);
    int srow1 = wid*32 + 16 + (lane >> 2);
    int scol  = (lane & 3) * 8;
    const ushort* gA0 = &xb[(size_t)(M0 + srow0)*KDIM + scol];
    const ushort* gA1 = &xb[(size_t)(M0 + srow1)*KDIM + scol];
    const ushort* gB0 = &wt[(size_t)(N0 + srow0)*KDIM + scol];
    const ushort* gB1 = &wt[(size_t)(N0 + srow1)*KDIM + scol];
    ushort* lA0 = &As[wid*32][0];
    ushort* lA1 = &As[wid*32 + 16][0];
    ushort* lB0 = &Bs[wid*32][0];
    ushort* lB1 = &Bs[wid*32 + 16][0];

    f32x4 acc[4][4] = {};
    for (int k0 = 0; k0 < KDIM; k0 += 32){
        gload16(gA0 + k0, lA0);
        gload16(gA1 + k0, lA1);
        gload16(gB0 + k0, lB0);
        gload16(gB1 + k0, lB1);
        __syncthreads();
        bf16x8 a[4], b[4];
#pragma unroll
        for (int mi = 0; mi < 4; mi++) a[mi] = *(const bf16x8*)(&As[wm*64 + mi*16 + lrow][lk*8]);
#pragma unroll
        for (int ni = 0; ni < 4; ni++) b[ni] = *(const bf16x8*)(&Bs[wn*64 + ni*16 + lrow][lk*8]);
#pragma unroll
        for (int mi = 0; mi < 4; mi++)
#pragma unroll
            for (int ni = 0; ni < 4; ni++)
                acc[mi][ni] = __builtin_amdgcn_mfma_f32_16x16x32_bf16(a[mi], b[ni], acc[mi][ni], 0, 0, 0);
        __syncthreads();
    }
#pragma unroll
    for (int mi = 0; mi < 4; mi++)
#pragma unroll
    for (int ni = 0; ni < 4; ni++){
        int gn = N0 + wn*64 + ni*16 + lrow;
        float bias = bqkv[gn];
        int which = gn >> 10;       // 0=q 1=k 2=v (uniform per block: 1024 % 128 == 0)
        int cn = gn & 1023;
        int h = cn >> 6, d = cn & 63;
        int gm0 = M0 + wm*64 + mi*16 + lk*4;
        if (which == 2){
            int bb = gm0 >> 11, pos0 = gm0 & 2047;
            ushort4 o = { f2bf(acc[mi][ni][0] + bias), f2bf(acc[mi][ni][1] + bias),
                          f2bf(acc[mi][ni][2] + bias), f2bf(acc[mi][ni][3] + bias) };
            *(ushort4*)(&vT[(((size_t)(bb*H_ + h))*D_ + d)*S_ + pos0]) = o;
        } else {
#pragma unroll
            for (int rr = 0; rr < 4; rr++){
                int gm = gm0 + rr;
                float val = acc[mi][ni][rr] + bias;
                float rot = __shfl_xor(val, 1);       // partner col (d^1), bias included
                int bb = gm >> 11, pos = gm & 2047;
                int out_idx = ((((bb*H_ + h)*S_) + pos))*D_ + d;
                float c = cosT[pos*64 + d], s = sinT[pos*64 + d];
                float o = val*c + ((d & 1) ? rot : -rot)*s;
                if (which == 0) o *= 0.125f;          // fold 1/sqrt(D) into q
                ((which == 0) ? qb : kb)[out_idx] = f2bf(o);
            }
        }
    }
}

// ---------------- causal flash attention, async-staged KV, swapped QK^T ----------------
// grid = (bh, qtile).  Block: 4 waves x 16 q-rows.  Full tiles need no causal mask;
// diagonal tile masks only s2==wid with the position-constant predicate lk*4+r > lrow.
__launch_bounds__(256)
__global__ void k_attn(const ushort* __restrict__ qb, const ushort* __restrict__ kb,
                       const ushort* __restrict__ vT, ushort* __restrict__ ob){
    __shared__ __align__(16) ushort Ks[64][72];
    __shared__ __align__(16) ushort Vs[64][72];
    __shared__ __align__(16) ushort ptile[4][16][72];
    int bh = blockIdx.x;
    int qt = blockIdx.y;
    int bb = bh >> 4, h = bh & 15;
    int tid = threadIdx.x, wid = tid >> 6, lane = tid & 63;
    int lrow = lane & 15, lk = lane >> 4;
    const ushort* qp = qb + (size_t)bh*S_*D_;
    const ushort* kp = kb + (size_t)bh*S_*D_;
    const ushort* vp = vT + (size_t)bh*D_*S_;
    int qrow = qt*64 + wid*16 + lrow;

    bf16x8 fq[2];
    fq[0] = *(const bf16x8*)(&qp[qrow*D_ + lk*8]);
    fq[1] = *(const bf16x8*)(&qp[qrow*D_ + 32 + lk*8]);

    f32x4 acc[4] = {};              // [d][q]: col=q=lrow, row d = nt*16 + lk*4 + r
    float m = -1e30f, l = 0.0f;

    int tr = tid >> 3;              // 0..31
    int tc = (tid & 7) * 8;         // 0..56

    // prologue: load tile 0 into regs
    int4 ra = *(const int4*)(&kp[tr*D_ + tc]);
    int4 rb = *(const int4*)(&kp[(tr + 32)*D_ + tc]);
    int4 rc = *(const int4*)(&vp[(size_t)tr*S_ + tc]);
    int4 rd = *(const int4*)(&vp[(size_t)(tr + 32)*S_ + tc]);

    const int jend = qt*64;
    for (int j0 = 0; ; j0 += 64){
        // write staged regs to LDS
        *(int4*)(&Ks[tr][tc])      = ra;
        *(int4*)(&Ks[tr + 32][tc]) = rb;
        *(int4*)(&Vs[tr][tc])      = rc;
        *(int4*)(&Vs[tr + 32][tc]) = rd;
        __syncthreads();
        bool diag = (j0 == jend);
        if (!diag){
            int j1 = j0 + 64;      // prefetch next tile; lands during compute
            ra = *(const int4*)(&kp[(j1 + tr)*D_ + tc]);
            rb = *(const int4*)(&kp[(j1 + tr + 32)*D_ + tc]);
            rc = *(const int4*)(&vp[(size_t)tr*S_ + j1 + tc]);
            rd = *(const int4*)(&vp[(size_t)(tr + 32)*S_ + j1 + tc]);
        }

        float p[4][4];
        float tmax = -1e30f;
        if (!diag){
#pragma unroll
            for (int s2 = 0; s2 < 4; s2++){
                bf16x8 k0 = *(const bf16x8*)(&Ks[s2*16 + lrow][lk*8]);
                bf16x8 k1 = *(const bf16x8*)(&Ks[s2*16 + lrow][32 + lk*8]);
                f32x4 z = {};
                z = __builtin_amdgcn_mfma_f32_16x16x32_bf16(k0, fq[0], z, 0, 0, 0);
                z = __builtin_amdgcn_mfma_f32_16x16x32_bf16(k1, fq[1], z, 0, 0, 0);
#pragma unroll
                for (int r = 0; r < 4; r++){ p[s2][r] = z[r]; tmax = fmaxf(tmax, z[r]); }
            }
        } else {
#pragma unroll
            for (int s2 = 0; s2 < 4; s2++){
                if (s2 <= wid){
                    bf16x8 k0 = *(const bf16x8*)(&Ks[s2*16 + lrow][lk*8]);
                    bf16x8 k1 = *(const bf16x8*)(&Ks[s2*16 + lrow][32 + lk*8]);
                    f32x4 z = {};
                    z = __builtin_amdgcn_mfma_f32_16x16x32_bf16(k0, fq[0], z, 0, 0, 0);
                    z = __builtin_amdgcn_mfma_f32_16x16x32_bf16(k1, fq[1], z, 0, 0, 0);
#pragma unroll
                    for (int r = 0; r < 4; r++){
                        float v = z[r];
                        if (s2 == wid && (lk*4 + r) > lrow) v = -1e30f;
                        p[s2][r] = v; tmax = fmaxf(tmax, v);
                    }
                } else {
#pragma unroll
                    for (int r = 0; r < 4; r++) p[s2][r] = -1e30f;
                }
            }
        }
        tmax = fmaxf(tmax, __shfl_xor(tmax, 16));
        tmax = fmaxf(tmax, __shfl_xor(tmax, 32));
        if (__any(tmax > m)){       // skip rescale when running max unchanged
            float newm = fmaxf(m, tmax);
            float resc = __expf(m - newm);
            m = newm;
            l *= resc;
#pragma unroll
            for (int nt = 0; nt < 4; nt++)
#pragma unroll
                for (int r = 0; r < 4; r++) acc[nt][r] *= resc;
        }
        float rsum = 0.0f;
#pragma unroll
        for (int s2 = 0; s2 < 4; s2++)
#pragma unroll
            for (int r = 0; r < 4; r++){
                float e = __expf(p[s2][r] - m);
                p[s2][r] = e;
                rsum += e;
            }
        rsum += __shfl_xor(rsum, 16);
        rsum += __shfl_xor(rsum, 32);
        l += rsum;

        // P^T -> per-wave LDS tile as P[q][key]
#pragma unroll
        for (int s2 = 0; s2 < 4; s2++){
            uint2 w;
            w.x = (unsigned)f2bf(p[s2][0]) | ((unsigned)f2bf(p[s2][1]) << 16);
            w.y = (unsigned)f2bf(p[s2][2]) | ((unsigned)f2bf(p[s2][3]) << 16);
            *(uint2*)(&ptile[wid][lrow][s2*16 + lk*4]) = w;
        }
        bool hi = !diag || (wid >= 2);
        bf16x8 fp0 = *(const bf16x8*)(&ptile[wid][lrow][lk*8]);
#pragma unroll
        for (int nt = 0; nt < 4; nt++){
            bf16x8 fv0 = *(const bf16x8*)(&Vs[nt*16 + lrow][lk*8]);
            acc[nt] = __builtin_amdgcn_mfma_f32_16x16x32_bf16(fv0, fp0, acc[nt], 0, 0, 0);
        }
        if (hi){
            bf16x8 fp1 = *(const bf16x8*)(&ptile[wid][lrow][32 + lk*8]);
#pragma unroll
            for (int nt = 0; nt < 4; nt++){
                bf16x8 fv1 = *(const bf16x8*)(&Vs[nt*16 + lrow][32 + lk*8]);
                acc[nt] = __builtin_amdgcn_mfma_f32_16x16x32_bf16(fv1, fp1, acc[nt], 0, 0, 0);
            }
        }
        __syncthreads();
        if (diag) break;
    }
    float rl = 1.0f / l;
#pragma unroll
    for (int nt = 0; nt < 4; nt++){
        ushort4 o = { f2bf(acc[nt][0]*rl), f2bf(acc[nt][1]*rl),
                      f2bf(acc[nt][2]*rl), f2bf(acc[nt][3]*rl) };
        *(ushort4*)(&ob[((size_t)(bb*S_ + qrow))*C_ + h*D_ + nt*16 + lk*4]) = o;
    }
}

// ---------------- proj GEMM (128x128 tile, global_load_lds) + bias -> fp32 out ----------------
__launch_bounds__(256)
__global__ void k_proj(const ushort* __restrict__ ab, const ushort* __restrict__ wt,
                       const float* __restrict__ bias, float* __restrict__ out){
    __shared__ __align__(16) ushort As[128][32];
    __shared__ __align__(16) ushort Bs[128][32];
    int M0 = blockIdx.y*128, N0 = blockIdx.x*128;
    int tid = threadIdx.x;
    int wid = tid >> 6, lane = tid & 63;
    int wm = wid >> 1, wn = wid & 1;
    int lrow = lane & 15, lk = lane >> 4;

    int srow0 = wid*32      + (lane >> 2);
    int srow1 = wid*32 + 16 + (lane >> 2);
    int scol  = (lane & 3) * 8;
    const ushort* gA0 = &ab[(size_t)(M0 + srow0)*KDIM + scol];
    const ushort* gA1 = &ab[(size_t)(M0 + srow1)*KDIM + scol];
    const ushort* gB0 = &wt[(size_t)(N0 + srow0)*KDIM + scol];
    const ushort* gB1 = &wt[(size_t)(N0 + srow1)*KDIM + scol];
    ushort* lA0 = &As[wid*32][0];
    ushort* lA1 = &As[wid*32 + 16][0];
    ushort* lB0 = &Bs[wid*32][0];
    ushort* lB1 = &Bs[wid*32 + 16][0];

    f32x4 acc[4][4] = {};
    for (int k0 = 0; k0 < KDIM; k0 += 32){
        gload16(gA0 + k0, lA0);
        gload16(gA1 + k0, lA1);
        gload16(gB0 + k0, lB0);
        gload16(gB1 + k0, lB1);
        __syncthreads();
        bf16x8 a[4], b[4];
#pragma unroll
        for (int mi = 0; mi < 4; mi++) a[mi] = *(const bf16x8*)(&As[wm*64 + mi*16 + lrow][lk*8]);
#pragma unroll
        for (int ni = 0; ni < 4; ni++) b[ni] = *(const bf16x8*)(&Bs[wn*64 + ni*16 + lrow][lk*8]);
#pragma unroll
        for (int mi = 0; mi < 4; mi++)
#pragma unroll
            for (int ni = 0; ni < 4; ni++)
                acc[mi][ni] = __builtin_amdgcn_mfma_f32_16x16x32_bf16(a[mi], b[ni], acc[mi][ni], 0, 0, 0);
        __syncthreads();
    }
#pragma unroll
    for (int mi = 0; mi < 4; mi++)
#pragma unroll
    for (int ni = 0; ni < 4; ni++){
        int gn = N0 + wn*64 + ni*16 + lrow;
        float bv = bias[gn];
#pragma unroll
        for (int rr = 0; rr < 4; rr++){
            int gm = M0 + wm*64 + mi*16 + lk*4 + rr;
            out[(size_t)gm*C_ + gn] = acc[mi][ni][rr] + bv;
        }
    }
}

extern "C" void kernel_launch(void* const* d_in, const int* in_sizes, int n_in,
                              void* d_out, int out_size, void* d_ws, size_t ws_size,
                              hipStream_t stream) {
    const float* x     = (const float*)d_in[0];
    const float* Wqkv  = (const float*)d_in[1];
    const float* bqkv  = (const float*)d_in[2];
    const float* Wproj = (const float*)d_in[3];
    const float* bproj = (const float*)d_in[4];
    float* out = (float*)d_out;

    char* ws = (char*)d_ws;
    ushort* xb   = (ushort*)(ws);                                  // 16 MB
    ushort* wqt  = (ushort*)(ws + (16u<<20));                      // 6 MB
    ushort* wpt  = (ushort*)(ws + (22u<<20));                      // 2 MB
    float*  cosT = (float*) (ws + (24u<<20));                      // 0.5 MB
    float*  sinT = (float*) (ws + (24u<<20) + (512u<<10));         // 0.5 MB
    ushort* qbuf = (ushort*)(ws + (25u<<20));                      // 16 MB (q pre-scaled by 0.125)
    ushort* kbuf = (ushort*)(ws + (41u<<20));                      // 16 MB
    ushort* vbuf = (ushort*)(ws + (57u<<20));                      // 16 MB (transposed [bh][D][S])
    ushort* obuf = (ushort*)(ws + (73u<<20));                      // 16 MB

    k_conv<<<(M_*KDIM/4 + 255)/256, 256, 0, stream>>>(x, xb, M_*KDIM/4);
    dim3 tb(32, 8);
    k_transpose<<<dim3(NQKV/32, KDIM/32), tb, 0, stream>>>(Wqkv, wqt, KDIM, NQKV);
    k_transpose<<<dim3(C_/32, KDIM/32), tb, 0, stream>>>(Wproj, wpt, KDIM, C_);
    k_rope_tab<<<(S_*D_ + 255)/256, 256, 0, stream>>>(cosT, sinT);

    k_qkv<<<dim3(NQKV/128, M_/128), 256, 0, stream>>>(xb, wqt, bqkv, cosT, sinT, qbuf, kbuf, vbuf);
    k_attn<<<dim3(B_*H_, S_/64), 256, 0, stream>>>(qbuf, kbuf, vbuf, obuf);
    k_proj<<<dim3(C_/128, M_/128), 256, 0, stream>>>(obuf, wpt, bproj, out);
}

// Round 6
// 223.180 us; speedup vs baseline: 2.8330x; 1.0443x over previous
//
#include <hip/hip_runtime.h>
#include <hip/hip_bf16.h>
#include <math.h>

#define B_ 4
#define S_ 2048
#define C_ 1024
#define H_ 16
#define D_ 64
#define M_ (B_*S_)      // 8192
#define NQKV (3*C_)     // 3072
#define KDIM C_         // 1024

typedef float f32x4 __attribute__((ext_vector_type(4)));
typedef short bf16x8 __attribute__((ext_vector_type(8)));

static __device__ __forceinline__ ushort f2bf(float f){
    __hip_bfloat16 h = __float2bfloat16(f);
    union { __hip_bfloat16 b; ushort u; } v; v.b = h;
    return v.u;
}

// async global->LDS, 16B per lane; lds dest = wave-uniform base + lane*16
static __device__ __forceinline__ void gload16(const ushort* g, ushort* l){
    __builtin_amdgcn_global_load_lds((__attribute__((address_space(1))) void*)g,
                                     (__attribute__((address_space(3))) void*)l,
                                     16, 0, 0);
}

// ---------------- convert x -> bf16 ----------------
__global__ void k_conv(const float* __restrict__ in, ushort* __restrict__ out, int n4){
    int i = blockIdx.x*blockDim.x + threadIdx.x;
    if (i < n4){
        float4 v = *(const float4*)(in + i*4);
        ushort4 o;
        o.x = f2bf(v.x); o.y = f2bf(v.y); o.z = f2bf(v.z); o.w = f2bf(v.w);
        *(ushort4*)(out + i*4) = o;
    }
}

// ---------------- transpose+convert W [R][Ccol] -> [Ccol][R] bf16 ----------------
__global__ void k_transpose(const float* __restrict__ in, ushort* __restrict__ out,
                            int R, int Ccol){
    __shared__ float tile[32][33];
    int c0 = blockIdx.x*32, r0 = blockIdx.y*32;
    int tx = threadIdx.x, ty = threadIdx.y;   // block (32,8)
    for (int j = ty; j < 32; j += 8)
        tile[j][tx] = in[(r0 + j)*Ccol + c0 + tx];
    __syncthreads();
    for (int j = ty; j < 32; j += 8)
        out[(size_t)(c0 + tx)*R + r0 + j] = f2bf(tile[j][tx]);
}

// ---------------- rope cos/sin tables [S][64] ----------------
__global__ void k_rope_tab(float* __restrict__ cosT, float* __restrict__ sinT){
    int t = blockIdx.x*blockDim.x + threadIdx.x;
    if (t >= S_*D_) return;
    int pos = t >> 6, j = t & 63;
    float invf = powf(10000.0f, -(float)(j & 31) / 32.0f);
    float ang = (float)pos * invf;
    cosT[t] = cosf(ang);
    sinT[t] = sinf(ang);
}

// ---------------- QKV GEMM (128x128 tile, global_load_lds) + bias + RoPE + scatter ----------------
// q output pre-scaled by 0.125*log2(e) so k_attn's softmax runs in exp2 domain.
__launch_bounds__(256)
__global__ void k_qkv(const ushort* __restrict__ xb, const ushort* __restrict__ wt,
                      const float* __restrict__ bqkv,
                      const float* __restrict__ cosT, const float* __restrict__ sinT,
                      ushort* __restrict__ qb, ushort* __restrict__ kb, ushort* __restrict__ vT){
    __shared__ __align__(16) ushort As[128][32];
    __shared__ __align__(16) ushort Bs[128][32];
    int M0 = blockIdx.y*128, N0 = blockIdx.x*128;
    int tid = threadIdx.x;
    int wid = tid >> 6, lane = tid & 63;
    int wm = wid >> 1, wn = wid & 1;
    int lrow = lane & 15, lk = lane >> 4;

    int srow0 = wid*32      + (lane >> 2);
    int srow1 = wid*32 + 16 + (lane >> 2);
    int scol  = (lane & 3) * 8;
    const ushort* gA0 = &xb[(size_t)(M0 + srow0)*KDIM + scol];
    const ushort* gA1 = &xb[(size_t)(M0 + srow1)*KDIM + scol];
    const ushort* gB0 = &wt[(size_t)(N0 + srow0)*KDIM + scol];
    const ushort* gB1 = &wt[(size_t)(N0 + srow1)*KDIM + scol];
    ushort* lA0 = &As[wid*32][0];
    ushort* lA1 = &As[wid*32 + 16][0];
    ushort* lB0 = &Bs[wid*32][0];
    ushort* lB1 = &Bs[wid*32 + 16][0];

    f32x4 acc[4][4] = {};
    for (int k0 = 0; k0 < KDIM; k0 += 32){
        gload16(gA0 + k0, lA0);
        gload16(gA1 + k0, lA1);
        gload16(gB0 + k0, lB0);
        gload16(gB1 + k0, lB1);
        __syncthreads();
        bf16x8 a[4], b[4];
#pragma unroll
        for (int mi = 0; mi < 4; mi++) a[mi] = *(const bf16x8*)(&As[wm*64 + mi*16 + lrow][lk*8]);
#pragma unroll
        for (int ni = 0; ni < 4; ni++) b[ni] = *(const bf16x8*)(&Bs[wn*64 + ni*16 + lrow][lk*8]);
#pragma unroll
        for (int mi = 0; mi < 4; mi++)
#pragma unroll
            for (int ni = 0; ni < 4; ni++)
                acc[mi][ni] = __builtin_amdgcn_mfma_f32_16x16x32_bf16(a[mi], b[ni], acc[mi][ni], 0, 0, 0);
        __syncthreads();
    }
#pragma unroll
    for (int mi = 0; mi < 4; mi++)
#pragma unroll
    for (int ni = 0; ni < 4; ni++){
        int gn = N0 + wn*64 + ni*16 + lrow;
        float bias = bqkv[gn];
        int which = gn >> 10;       // 0=q 1=k 2=v (uniform per block: 1024 % 128 == 0)
        int cn = gn & 1023;
        int h = cn >> 6, d = cn & 63;
        int gm0 = M0 + wm*64 + mi*16 + lk*4;
        if (which == 2){
            int bb = gm0 >> 11, pos0 = gm0 & 2047;
            ushort4 o = { f2bf(acc[mi][ni][0] + bias), f2bf(acc[mi][ni][1] + bias),
                          f2bf(acc[mi][ni][2] + bias), f2bf(acc[mi][ni][3] + bias) };
            *(ushort4*)(&vT[(((size_t)(bb*H_ + h))*D_ + d)*S_ + pos0]) = o;
        } else {
#pragma unroll
            for (int rr = 0; rr < 4; rr++){
                int gm = gm0 + rr;
                float val = acc[mi][ni][rr] + bias;
                float rot = __shfl_xor(val, 1);       // partner col (d^1), bias included
                int bb = gm >> 11, pos = gm & 2047;
                int out_idx = ((((bb*H_ + h)*S_) + pos))*D_ + d;
                float c = cosT[pos*64 + d], s = sinT[pos*64 + d];
                float o = val*c + ((d & 1) ? rot : -rot)*s;
                if (which == 0) o *= 0.18033688f;     // (1/sqrt(D)) * log2(e)
                ((which == 0) ? qb : kb)[out_idx] = f2bf(o);
            }
        }
    }
}

// ---------------- causal flash attention, async-staged KV, swapped QK^T, XOR-swizzled LDS ----
// grid = (bh, qtile), heavy-first (qt = 31 - blockIdx.y).  Block: 4 waves x 16 q-rows.
// LDS 16B-unit swizzle: unit u at row r stored at u ^ (r&7); same XOR on write and read.
__launch_bounds__(256)
__global__ void k_attn(const ushort* __restrict__ qb, const ushort* __restrict__ kb,
                       const ushort* __restrict__ vT, ushort* __restrict__ ob){
    __shared__ __align__(16) ushort Ks[64][64];
    __shared__ __align__(16) ushort Vs[64][64];
    __shared__ __align__(16) ushort ptile[4][16][64];
    int bh = blockIdx.x;
    int qt = (gridDim.y - 1) - blockIdx.y;      // heavy blocks dispatch first
    int bb = bh >> 4, h = bh & 15;
    int tid = threadIdx.x, wid = tid >> 6, lane = tid & 63;
    int lrow = lane & 15, lk = lane >> 4;
    int sw = lrow & 7;
    const ushort* qp = qb + (size_t)bh*S_*D_;
    const ushort* kp = kb + (size_t)bh*S_*D_;
    const ushort* vp = vT + (size_t)bh*D_*S_;
    int qrow = qt*64 + wid*16 + lrow;

    bf16x8 fq[2];
    fq[0] = *(const bf16x8*)(&qp[qrow*D_ + lk*8]);
    fq[1] = *(const bf16x8*)(&qp[qrow*D_ + 32 + lk*8]);

    f32x4 acc[4] = {};              // [d][q]: col=q=lrow, row d = nt*16 + lk*4 + r
    float m = -1e30f, l = 0.0f;

    int tr  = tid >> 3;             // 0..31
    int tcu = tid & 7;              // 16B unit 0..7
    int twu = (tcu ^ (tr & 7)) * 8; // swizzled element offset for stage writes
    int tc  = tcu * 8;              // global element offset

    // prologue: load tile 0 into regs
    int4 ra = *(const int4*)(&kp[tr*D_ + tc]);
    int4 rb = *(const int4*)(&kp[(tr + 32)*D_ + tc]);
    int4 rc = *(const int4*)(&vp[(size_t)tr*S_ + tc]);
    int4 rd = *(const int4*)(&vp[(size_t)(tr + 32)*S_ + tc]);

    const int jend = qt*64;
    for (int j0 = 0; ; j0 += 64){
        *(int4*)(&Ks[tr][twu])      = ra;
        *(int4*)(&Ks[tr + 32][twu]) = rb;
        *(int4*)(&Vs[tr][twu])      = rc;
        *(int4*)(&Vs[tr + 32][twu]) = rd;
        __syncthreads();
        bool diag = (j0 == jend);
        if (!diag){
            int j1 = j0 + 64;      // prefetch next tile; lands during compute
            ra = *(const int4*)(&kp[(j1 + tr)*D_ + tc]);
            rb = *(const int4*)(&kp[(j1 + tr + 32)*D_ + tc]);
            rc = *(const int4*)(&vp[(size_t)tr*S_ + j1 + tc]);
            rd = *(const int4*)(&vp[(size_t)(tr + 32)*S_ + j1 + tc]);
        }

        float p[4][4];
        float tmax = -1e30f;
        if (!diag){
#pragma unroll
            for (int s2 = 0; s2 < 4; s2++){
                bf16x8 k0 = *(const bf16x8*)(&Ks[s2*16 + lrow][(lk ^ sw)*8]);
                bf16x8 k1 = *(const bf16x8*)(&Ks[s2*16 + lrow][((4 + lk) ^ sw)*8]);
                f32x4 z = {};
                z = __builtin_amdgcn_mfma_f32_16x16x32_bf16(k0, fq[0], z, 0, 0, 0);
                z = __builtin_amdgcn_mfma_f32_16x16x32_bf16(k1, fq[1], z, 0, 0, 0);
#pragma unroll
                for (int r = 0; r < 4; r++){ p[s2][r] = z[r]; tmax = fmaxf(tmax, z[r]); }
            }
        } else {
#pragma unroll
            for (int s2 = 0; s2 < 4; s2++){
                if (s2 <= wid){
                    bf16x8 k0 = *(const bf16x8*)(&Ks[s2*16 + lrow][(lk ^ sw)*8]);
                    bf16x8 k1 = *(const bf16x8*)(&Ks[s2*16 + lrow][((4 + lk) ^ sw)*8]);
                    f32x4 z = {};
                    z = __builtin_amdgcn_mfma_f32_16x16x32_bf16(k0, fq[0], z, 0, 0, 0);
                    z = __builtin_amdgcn_mfma_f32_16x16x32_bf16(k1, fq[1], z, 0, 0, 0);
#pragma unroll
                    for (int r = 0; r < 4; r++){
                        float v = z[r];
                        if (s2 == wid && (lk*4 + r) > lrow) v = -1e30f;
                        p[s2][r] = v; tmax = fmaxf(tmax, v);
                    }
                } else {
#pragma unroll
                    for (int r = 0; r < 4; r++) p[s2][r] = -1e30f;
                }
            }
        }
        tmax = fmaxf(tmax, __shfl_xor(tmax, 16));
        tmax = fmaxf(tmax, __shfl_xor(tmax, 32));
        if (__any(tmax > m)){       // skip rescale when running max unchanged
            float newm = fmaxf(m, tmax);
            float resc = exp2f(m - newm);
            m = newm;
            l *= resc;
#pragma unroll
            for (int nt = 0; nt < 4; nt++)
#pragma unroll
                for (int r = 0; r < 4; r++) acc[nt][r] *= resc;
        }
        float rsum = 0.0f;
#pragma unroll
        for (int s2 = 0; s2 < 4; s2++)
#pragma unroll
            for (int r = 0; r < 4; r++){
                float e = exp2f(p[s2][r] - m);
                p[s2][r] = e;
                rsum += e;
            }
        rsum += __shfl_xor(rsum, 16);
        rsum += __shfl_xor(rsum, 32);
        l += rsum;

        // P^T -> per-wave LDS tile as P[q][key], swizzled b64 writes
#pragma unroll
        for (int s2 = 0; s2 < 4; s2++){
            uint2 w;
            w.x = (unsigned)f2bf(p[s2][0]) | ((unsigned)f2bf(p[s2][1]) << 16);
            w.y = (unsigned)f2bf(p[s2][2]) | ((unsigned)f2bf(p[s2][3]) << 16);
            *(uint2*)(&ptile[wid][lrow][((s2*2 + (lk >> 1)) ^ sw)*8 + (lk & 1)*4]) = w;
        }
        bool hi = !diag || (wid >= 2);
        bf16x8 fp0 = *(const bf16x8*)(&ptile[wid][lrow][(lk ^ sw)*8]);
#pragma unroll
        for (int nt = 0; nt < 4; nt++){
            bf16x8 fv0 = *(const bf16x8*)(&Vs[nt*16 + lrow][(lk ^ sw)*8]);
            acc[nt] = __builtin_amdgcn_mfma_f32_16x16x32_bf16(fv0, fp0, acc[nt], 0, 0, 0);
        }
        if (hi){
            bf16x8 fp1 = *(const bf16x8*)(&ptile[wid][lrow][((4 + lk) ^ sw)*8]);
#pragma unroll
            for (int nt = 0; nt < 4; nt++){
                bf16x8 fv1 = *(const bf16x8*)(&Vs[nt*16 + lrow][((4 + lk) ^ sw)*8]);
                acc[nt] = __builtin_amdgcn_mfma_f32_16x16x32_bf16(fv1, fp1, acc[nt], 0, 0, 0);
            }
        }
        __syncthreads();
        if (diag) break;
    }
    float rl = 1.0f / l;
#pragma unroll
    for (int nt = 0; nt < 4; nt++){
        ushort4 o = { f2bf(acc[nt][0]*rl), f2bf(acc[nt][1]*rl),
                      f2bf(acc[nt][2]*rl), f2bf(acc[nt][3]*rl) };
        *(ushort4*)(&ob[((size_t)(bb*S_ + qrow))*C_ + h*D_ + nt*16 + lk*4]) = o;
    }
}

// ---------------- proj GEMM (128x128 tile, global_load_lds) + bias -> fp32 out ----------------
__launch_bounds__(256)
__global__ void k_proj(const ushort* __restrict__ ab, const ushort* __restrict__ wt,
                       const float* __restrict__ bias, float* __restrict__ out){
    __shared__ __align__(16) ushort As[128][32];
    __shared__ __align__(16) ushort Bs[128][32];
    int M0 = blockIdx.y*128, N0 = blockIdx.x*128;
    int tid = threadIdx.x;
    int wid = tid >> 6, lane = tid & 63;
    int wm = wid >> 1, wn = wid & 1;
    int lrow = lane & 15, lk = lane >> 4;

    int srow0 = wid*32      + (lane >> 2);
    int srow1 = wid*32 + 16 + (lane >> 2);
    int scol  = (lane & 3) * 8;
    const ushort* gA0 = &ab[(size_t)(M0 + srow0)*KDIM + scol];
    const ushort* gA1 = &ab[(size_t)(M0 + srow1)*KDIM + scol];
    const ushort* gB0 = &wt[(size_t)(N0 + srow0)*KDIM + scol];
    const ushort* gB1 = &wt[(size_t)(N0 + srow1)*KDIM + scol];
    ushort* lA0 = &As[wid*32][0];
    ushort* lA1 = &As[wid*32 + 16][0];
    ushort* lB0 = &Bs[wid*32][0];
    ushort* lB1 = &Bs[wid*32 + 16][0];

    f32x4 acc[4][4] = {};
    for (int k0 = 0; k0 < KDIM; k0 += 32){
        gload16(gA0 + k0, lA0);
        gload16(gA1 + k0, lA1);
        gload16(gB0 + k0, lB0);
        gload16(gB1 + k0, lB1);
        __syncthreads();
        bf16x8 a[4], b[4];
#pragma unroll
        for (int mi = 0; mi < 4; mi++) a[mi] = *(const bf16x8*)(&As[wm*64 + mi*16 + lrow][lk*8]);
#pragma unroll
        for (int ni = 0; ni < 4; ni++) b[ni] = *(const bf16x8*)(&Bs[wn*64 + ni*16 + lrow][lk*8]);
#pragma unroll
        for (int mi = 0; mi < 4; mi++)
#pragma unroll
            for (int ni = 0; ni < 4; ni++)
                acc[mi][ni] = __builtin_amdgcn_mfma_f32_16x16x32_bf16(a[mi], b[ni], acc[mi][ni], 0, 0, 0);
        __syncthreads();
    }
#pragma unroll
    for (int mi = 0; mi < 4; mi++)
#pragma unroll
    for (int ni = 0; ni < 4; ni++){
        int gn = N0 + wn*64 + ni*16 + lrow;
        float bv = bias[gn];
#pragma unroll
        for (int rr = 0; rr < 4; rr++){
            int gm = M0 + wm*64 + mi*16 + lk*4 + rr;
            out[(size_t)gm*C_ + gn] = acc[mi][ni][rr] + bv;
        }
    }
}

extern "C" void kernel_launch(void* const* d_in, const int* in_sizes, int n_in,
                              void* d_out, int out_size, void* d_ws, size_t ws_size,
                              hipStream_t stream) {
    const float* x     = (const float*)d_in[0];
    const float* Wqkv  = (const float*)d_in[1];
    const float* bqkv  = (const float*)d_in[2];
    const float* Wproj = (const float*)d_in[3];
    const float* bproj = (const float*)d_in[4];
    float* out = (float*)d_out;

    char* ws = (char*)d_ws;
    ushort* xb   = (ushort*)(ws);                                  // 16 MB
    ushort* wqt  = (ushort*)(ws + (16u<<20));                      // 6 MB
    ushort* wpt  = (ushort*)(ws + (22u<<20));                      // 2 MB
    float*  cosT = (float*) (ws + (24u<<20));                      // 0.5 MB
    float*  sinT = (float*) (ws + (24u<<20) + (512u<<10));         // 0.5 MB
    ushort* qbuf = (ushort*)(ws + (25u<<20));                      // 16 MB (q pre-scaled, exp2 domain)
    ushort* kbuf = (ushort*)(ws + (41u<<20));                      // 16 MB
    ushort* vbuf = (ushort*)(ws + (57u<<20));                      // 16 MB (transposed [bh][D][S])
    ushort* obuf = (ushort*)(ws + (73u<<20));                      // 16 MB

    k_conv<<<(M_*KDIM/4 + 255)/256, 256, 0, stream>>>(x, xb, M_*KDIM/4);
    dim3 tb(32, 8);
    k_transpose<<<dim3(NQKV/32, KDIM/32), tb, 0, stream>>>(Wqkv, wqt, KDIM, NQKV);
    k_transpose<<<dim3(C_/32, KDIM/32), tb, 0, stream>>>(Wproj, wpt, KDIM, C_);
    k_rope_tab<<<(S_*D_ + 255)/256, 256, 0, stream>>>(cosT, sinT);

    k_qkv<<<dim3(NQKV/128, M_/128), 256, 0, stream>>>(xb, wqt, bqkv, cosT, sinT, qbuf, kbuf, vbuf);
    k_attn<<<dim3(B_*H_, S_/64), 256, 0, stream>>>(qbuf, kbuf, vbuf, obuf);
    k_proj<<<dim3(C_/128, M_/128), 256, 0, stream>>>(obuf, wpt, bproj, out);
}

// Round 7
// 201.255 us; speedup vs baseline: 3.1416x; 1.1089x over previous
//
#include <hip/hip_runtime.h>
#include <hip/hip_bf16.h>
#include <math.h>

#define B_ 4
#define S_ 2048
#define C_ 1024
#define H_ 16
#define D_ 64
#define M_ (B_*S_)      // 8192
#define NQKV (3*C_)     // 3072
#define KDIM C_         // 1024

typedef float f32x4 __attribute__((ext_vector_type(4)));
typedef short bf16x8 __attribute__((ext_vector_type(8)));

static __device__ __forceinline__ ushort f2bf(float f){
    __hip_bfloat16 h = __float2bfloat16(f);
    union { __hip_bfloat16 b; ushort u; } v; v.b = h;
    return v.u;
}

// async global->LDS, 16B per lane; lds dest = wave-uniform base + lane*16 (linear)
static __device__ __forceinline__ void gload16(const ushort* g, ushort* l){
    __builtin_amdgcn_global_load_lds((__attribute__((address_space(1))) void*)g,
                                     (__attribute__((address_space(3))) void*)l,
                                     16, 0, 0);
}

// ---------------- convert x -> bf16 ----------------
__global__ void k_conv(const float* __restrict__ in, ushort* __restrict__ out, int n4){
    int i = blockIdx.x*blockDim.x + threadIdx.x;
    if (i < n4){
        float4 v = *(const float4*)(in + i*4);
        ushort4 o;
        o.x = f2bf(v.x); o.y = f2bf(v.y); o.z = f2bf(v.z); o.w = f2bf(v.w);
        *(ushort4*)(out + i*4) = o;
    }
}

// ---------------- transpose+convert W [R][Ccol] -> [Ccol][R] bf16 ----------------
__global__ void k_transpose(const float* __restrict__ in, ushort* __restrict__ out,
                            int R, int Ccol){
    __shared__ float tile[32][33];
    int c0 = blockIdx.x*32, r0 = blockIdx.y*32;
    int tx = threadIdx.x, ty = threadIdx.y;   // block (32,8)
    for (int j = ty; j < 32; j += 8)
        tile[j][tx] = in[(r0 + j)*Ccol + c0 + tx];
    __syncthreads();
    for (int j = ty; j < 32; j += 8)
        out[(size_t)(c0 + tx)*R + r0 + j] = f2bf(tile[j][tx]);
}

// ---------------- rope cos/sin tables [S][64] ----------------
__global__ void k_rope_tab(float* __restrict__ cosT, float* __restrict__ sinT){
    int t = blockIdx.x*blockDim.x + threadIdx.x;
    if (t >= S_*D_) return;
    int pos = t >> 6, j = t & 63;
    float invf = powf(10000.0f, -(float)(j & 31) / 32.0f);
    float ang = (float)pos * invf;
    cosT[t] = cosf(ang);
    sinT[t] = sinf(ang);
}

// ============ 256x128-tile, 8-wave, double-buffered GEMM body (BK=32) ============
// LDS read swizzle: 16B unit u at row r stored at u ^ ((r>>1)&3); source pre-swizzled,
// dest linear (global_load_lds constraint).  One __syncthreads per K-step; next step's
// loads issued before compute so latency hides under ds_read+MFMA.

// ---------------- QKV GEMM + bias + RoPE + scatter; V transposed ----------------
// q output pre-scaled by 0.125*log2(e) so k_attn's softmax runs in exp2 domain.
__launch_bounds__(512, 4)
__global__ void k_qkv(const ushort* __restrict__ xb, const ushort* __restrict__ wt,
                      const float* __restrict__ bqkv,
                      const float* __restrict__ cosT, const float* __restrict__ sinT,
                      ushort* __restrict__ qb, ushort* __restrict__ kb, ushort* __restrict__ vT){
    __shared__ __align__(16) ushort As[2][256][32];
    __shared__ __align__(16) ushort Bs[2][128][32];
    int bid = blockIdx.x;                       // 768 blocks, XCD-grouped (A-panel-major)
    int lin = (bid & 7)*96 + (bid >> 3);
    int bx = lin % 24, by = lin / 24;
    int M0 = by*256, N0 = bx*128;
    int tid = threadIdx.x;
    int wid = tid >> 6, lane = tid & 63;
    int wm = wid >> 1, wn = wid & 1;
    int lrow = lane & 15, lk = lane >> 4;
    int swu = (lrow >> 1) & 3;                  // read-side XOR (row bits [2:1])

    // staging: A = 16 chunks of 16 rows (wave w: chunks w, w+8); B = 8 chunks (wave w: chunk w)
    int scol = (((lane & 3) ^ ((lane >> 3) & 3))) * 8;   // pre-swizzled source column
    const ushort* gA0 = &xb[(size_t)(M0 + wid*16 + (lane >> 2))*KDIM + scol];
    const ushort* gA1 = gA0 + (size_t)128*KDIM;
    const ushort* gB0 = &wt[(size_t)(N0 + wid*16 + (lane >> 2))*KDIM + scol];

    f32x4 acc[4][4] = {};
    int cur = 0;
    // prologue: stage K-step 0 into buf 0
    gload16(gA0, &As[0][wid*16][0]);
    gload16(gA1, &As[0][128 + wid*16][0]);
    gload16(gB0, &Bs[0][wid*16][0]);
    __syncthreads();

    for (int k0 = 0; k0 < KDIM; k0 += 32){
        int nk = k0 + 32;
        if (nk < KDIM){                          // prefetch next step into other buffer
            gload16(gA0 + nk, &As[cur^1][wid*16][0]);
            gload16(gA1 + nk, &As[cur^1][128 + wid*16][0]);
            gload16(gB0 + nk, &Bs[cur^1][wid*16][0]);
        }
        bf16x8 a[4], b[4];
#pragma unroll
        for (int mi = 0; mi < 4; mi++)
            a[mi] = *(const bf16x8*)(&As[cur][wm*64 + mi*16 + lrow][(lk ^ swu)*8]);
#pragma unroll
        for (int ni = 0; ni < 4; ni++)
            b[ni] = *(const bf16x8*)(&Bs[cur][wn*64 + ni*16 + lrow][(lk ^ swu)*8]);
#pragma unroll
        for (int mi = 0; mi < 4; mi++)
#pragma unroll
            for (int ni = 0; ni < 4; ni++)
                acc[mi][ni] = __builtin_amdgcn_mfma_f32_16x16x32_bf16(a[mi], b[ni], acc[mi][ni], 0, 0, 0);
        __syncthreads();                          // drains prefetch vmcnt + syncs readers
        cur ^= 1;
    }
#pragma unroll
    for (int mi = 0; mi < 4; mi++)
#pragma unroll
    for (int ni = 0; ni < 4; ni++){
        int gn = N0 + wn*64 + ni*16 + lrow;
        float bias = bqkv[gn];
        int which = gn >> 10;       // 0=q 1=k 2=v (uniform per block: 1024 % 128 == 0)
        int cn = gn & 1023;
        int h = cn >> 6, d = cn & 63;
        int gm0 = M0 + wm*64 + mi*16 + lk*4;
        if (which == 2){
            int bb = gm0 >> 11, pos0 = gm0 & 2047;
            ushort4 o = { f2bf(acc[mi][ni][0] + bias), f2bf(acc[mi][ni][1] + bias),
                          f2bf(acc[mi][ni][2] + bias), f2bf(acc[mi][ni][3] + bias) };
            *(ushort4*)(&vT[(((size_t)(bb*H_ + h))*D_ + d)*S_ + pos0]) = o;
        } else {
#pragma unroll
            for (int rr = 0; rr < 4; rr++){
                int gm = gm0 + rr;
                float val = acc[mi][ni][rr] + bias;
                float rot = __shfl_xor(val, 1);       // partner col (d^1), bias included
                int bb = gm >> 11, pos = gm & 2047;
                int out_idx = ((((bb*H_ + h)*S_) + pos))*D_ + d;
                float c = cosT[pos*64 + d], s = sinT[pos*64 + d];
                float o = val*c + ((d & 1) ? rot : -rot)*s;
                if (which == 0) o *= 0.18033688f;     // (1/sqrt(D)) * log2(e)
                ((which == 0) ? qb : kb)[out_idx] = f2bf(o);
            }
        }
    }
}

// ---------------- proj GEMM (256x128 dbuf) + bias -> fp32 out ----------------
__launch_bounds__(512, 4)
__global__ void k_proj(const ushort* __restrict__ ab, const ushort* __restrict__ wt,
                       const float* __restrict__ bias, float* __restrict__ out){
    __shared__ __align__(16) ushort As[2][256][32];
    __shared__ __align__(16) ushort Bs[2][128][32];
    int bid = blockIdx.x;                       // 256 blocks, XCD-grouped
    int lin = (bid & 7)*32 + (bid >> 3);
    int bx = lin & 7, by = lin >> 3;
    int M0 = by*256, N0 = bx*128;
    int tid = threadIdx.x;
    int wid = tid >> 6, lane = tid & 63;
    int wm = wid >> 1, wn = wid & 1;
    int lrow = lane & 15, lk = lane >> 4;
    int swu = (lrow >> 1) & 3;

    int scol = (((lane & 3) ^ ((lane >> 3) & 3))) * 8;
    const ushort* gA0 = &ab[(size_t)(M0 + wid*16 + (lane >> 2))*KDIM + scol];
    const ushort* gA1 = gA0 + (size_t)128*KDIM;
    const ushort* gB0 = &wt[(size_t)(N0 + wid*16 + (lane >> 2))*KDIM + scol];

    f32x4 acc[4][4] = {};
    int cur = 0;
    gload16(gA0, &As[0][wid*16][0]);
    gload16(gA1, &As[0][128 + wid*16][0]);
    gload16(gB0, &Bs[0][wid*16][0]);
    __syncthreads();

    for (int k0 = 0; k0 < KDIM; k0 += 32){
        int nk = k0 + 32;
        if (nk < KDIM){
            gload16(gA0 + nk, &As[cur^1][wid*16][0]);
            gload16(gA1 + nk, &As[cur^1][128 + wid*16][0]);
            gload16(gB0 + nk, &Bs[cur^1][wid*16][0]);
        }
        bf16x8 a[4], b[4];
#pragma unroll
        for (int mi = 0; mi < 4; mi++)
            a[mi] = *(const bf16x8*)(&As[cur][wm*64 + mi*16 + lrow][(lk ^ swu)*8]);
#pragma unroll
        for (int ni = 0; ni < 4; ni++)
            b[ni] = *(const bf16x8*)(&Bs[cur][wn*64 + ni*16 + lrow][(lk ^ swu)*8]);
#pragma unroll
        for (int mi = 0; mi < 4; mi++)
#pragma unroll
            for (int ni = 0; ni < 4; ni++)
                acc[mi][ni] = __builtin_amdgcn_mfma_f32_16x16x32_bf16(a[mi], b[ni], acc[mi][ni], 0, 0, 0);
        __syncthreads();
        cur ^= 1;
    }
#pragma unroll
    for (int mi = 0; mi < 4; mi++)
#pragma unroll
    for (int ni = 0; ni < 4; ni++){
        int gn = N0 + wn*64 + ni*16 + lrow;
        float bv = bias[gn];
#pragma unroll
        for (int rr = 0; rr < 4; rr++){
            int gm = M0 + wm*64 + mi*16 + lk*4 + rr;
            out[(size_t)gm*C_ + gn] = acc[mi][ni][rr] + bv;
        }
    }
}

// ---------------- causal flash attention, async-staged KV, swapped QK^T, XOR-swizzled LDS ----
// grid = (bh, qtile), heavy-first (qt = 31 - blockIdx.y).  Block: 4 waves x 16 q-rows.
// LDS 16B-unit swizzle: unit u at row r stored at u ^ (r&7); same XOR on write and read.
__launch_bounds__(256)
__global__ void k_attn(const ushort* __restrict__ qb, const ushort* __restrict__ kb,
                       const ushort* __restrict__ vT, ushort* __restrict__ ob){
    __shared__ __align__(16) ushort Ks[64][64];
    __shared__ __align__(16) ushort Vs[64][64];
    __shared__ __align__(16) ushort ptile[4][16][64];
    int bh = blockIdx.x;
    int qt = (gridDim.y - 1) - blockIdx.y;      // heavy blocks dispatch first
    int bb = bh >> 4, h = bh & 15;
    int tid = threadIdx.x, wid = tid >> 6, lane = tid & 63;
    int lrow = lane & 15, lk = lane >> 4;
    int sw = lrow & 7;
    const ushort* qp = qb + (size_t)bh*S_*D_;
    const ushort* kp = kb + (size_t)bh*S_*D_;
    const ushort* vp = vT + (size_t)bh*D_*S_;
    int qrow = qt*64 + wid*16 + lrow;

    bf16x8 fq[2];
    fq[0] = *(const bf16x8*)(&qp[qrow*D_ + lk*8]);
    fq[1] = *(const bf16x8*)(&qp[qrow*D_ + 32 + lk*8]);

    f32x4 acc[4] = {};              // [d][q]: col=q=lrow, row d = nt*16 + lk*4 + r
    float m = -1e30f, l = 0.0f;

    int tr  = tid >> 3;             // 0..31
    int tcu = tid & 7;              // 16B unit 0..7
    int twu = (tcu ^ (tr & 7)) * 8; // swizzled element offset for stage writes
    int tc  = tcu * 8;              // global element offset

    // prologue: load tile 0 into regs
    int4 ra = *(const int4*)(&kp[tr*D_ + tc]);
    int4 rb = *(const int4*)(&kp[(tr + 32)*D_ + tc]);
    int4 rc = *(const int4*)(&vp[(size_t)tr*S_ + tc]);
    int4 rd = *(const int4*)(&vp[(size_t)(tr + 32)*S_ + tc]);

    const int jend = qt*64;
    for (int j0 = 0; ; j0 += 64){
        *(int4*)(&Ks[tr][twu])      = ra;
        *(int4*)(&Ks[tr + 32][twu]) = rb;
        *(int4*)(&Vs[tr][twu])      = rc;
        *(int4*)(&Vs[tr + 32][twu]) = rd;
        __syncthreads();
        bool diag = (j0 == jend);
        if (!diag){
            int j1 = j0 + 64;      // prefetch next tile; lands during compute
            ra = *(const int4*)(&kp[(j1 + tr)*D_ + tc]);
            rb = *(const int4*)(&kp[(j1 + tr + 32)*D_ + tc]);
            rc = *(const int4*)(&vp[(size_t)tr*S_ + j1 + tc]);
            rd = *(const int4*)(&vp[(size_t)(tr + 32)*S_ + j1 + tc]);
        }

        float p[4][4];
        float tmax = -1e30f;
        if (!diag){
#pragma unroll
            for (int s2 = 0; s2 < 4; s2++){
                bf16x8 k0 = *(const bf16x8*)(&Ks[s2*16 + lrow][(lk ^ sw)*8]);
                bf16x8 k1 = *(const bf16x8*)(&Ks[s2*16 + lrow][((4 + lk) ^ sw)*8]);
                f32x4 z = {};
                z = __builtin_amdgcn_mfma_f32_16x16x32_bf16(k0, fq[0], z, 0, 0, 0);
                z = __builtin_amdgcn_mfma_f32_16x16x32_bf16(k1, fq[1], z, 0, 0, 0);
#pragma unroll
                for (int r = 0; r < 4; r++){ p[s2][r] = z[r]; tmax = fmaxf(tmax, z[r]); }
            }
        } else {
#pragma unroll
            for (int s2 = 0; s2 < 4; s2++){
                if (s2 <= wid){
                    bf16x8 k0 = *(const bf16x8*)(&Ks[s2*16 + lrow][(lk ^ sw)*8]);
                    bf16x8 k1 = *(const bf16x8*)(&Ks[s2*16 + lrow][((4 + lk) ^ sw)*8]);
                    f32x4 z = {};
                    z = __builtin_amdgcn_mfma_f32_16x16x32_bf16(k0, fq[0], z, 0, 0, 0);
                    z = __builtin_amdgcn_mfma_f32_16x16x32_bf16(k1, fq[1], z, 0, 0, 0);
#pragma unroll
                    for (int r = 0; r < 4; r++){
                        float v = z[r];
                        if (s2 == wid && (lk*4 + r) > lrow) v = -1e30f;
                        p[s2][r] = v; tmax = fmaxf(tmax, v);
                    }
                } else {
#pragma unroll
                    for (int r = 0; r < 4; r++) p[s2][r] = -1e30f;
                }
            }
        }
        tmax = fmaxf(tmax, __shfl_xor(tmax, 16));
        tmax = fmaxf(tmax, __shfl_xor(tmax, 32));
        if (__any(tmax > m)){       // skip rescale when running max unchanged
            float newm = fmaxf(m, tmax);
            float resc = exp2f(m - newm);
            m = newm;
            l *= resc;
#pragma unroll
            for (int nt = 0; nt < 4; nt++)
#pragma unroll
                for (int r = 0; r < 4; r++) acc[nt][r] *= resc;
        }
        float rsum = 0.0f;
#pragma unroll
        for (int s2 = 0; s2 < 4; s2++)
#pragma unroll
            for (int r = 0; r < 4; r++){
                float e = exp2f(p[s2][r] - m);
                p[s2][r] = e;
                rsum += e;
            }
        rsum += __shfl_xor(rsum, 16);
        rsum += __shfl_xor(rsum, 32);
        l += rsum;

        // P^T -> per-wave LDS tile as P[q][key], swizzled b64 writes
#pragma unroll
        for (int s2 = 0; s2 < 4; s2++){
            uint2 w;
            w.x = (unsigned)f2bf(p[s2][0]) | ((unsigned)f2bf(p[s2][1]) << 16);
            w.y = (unsigned)f2bf(p[s2][2]) | ((unsigned)f2bf(p[s2][3]) << 16);
            *(uint2*)(&ptile[wid][lrow][((s2*2 + (lk >> 1)) ^ sw)*8 + (lk & 1)*4]) = w;
        }
        bool hi = !diag || (wid >= 2);
        bf16x8 fp0 = *(const bf16x8*)(&ptile[wid][lrow][(lk ^ sw)*8]);
#pragma unroll
        for (int nt = 0; nt < 4; nt++){
            bf16x8 fv0 = *(const bf16x8*)(&Vs[nt*16 + lrow][(lk ^ sw)*8]);
            acc[nt] = __builtin_amdgcn_mfma_f32_16x16x32_bf16(fv0, fp0, acc[nt], 0, 0, 0);
        }
        if (hi){
            bf16x8 fp1 = *(const bf16x8*)(&ptile[wid][lrow][((4 + lk) ^ sw)*8]);
#pragma unroll
            for (int nt = 0; nt < 4; nt++){
                bf16x8 fv1 = *(const bf16x8*)(&Vs[nt*16 + lrow][((4 + lk) ^ sw)*8]);
                acc[nt] = __builtin_amdgcn_mfma_f32_16x16x32_bf16(fv1, fp1, acc[nt], 0, 0, 0);
            }
        }
        __syncthreads();
        if (diag) break;
    }
    float rl = 1.0f / l;
#pragma unroll
    for (int nt = 0; nt < 4; nt++){
        ushort4 o = { f2bf(acc[nt][0]*rl), f2bf(acc[nt][1]*rl),
                      f2bf(acc[nt][2]*rl), f2bf(acc[nt][3]*rl) };
        *(ushort4*)(&ob[((size_t)(bb*S_ + qrow))*C_ + h*D_ + nt*16 + lk*4]) = o;
    }
}

extern "C" void kernel_launch(void* const* d_in, const int* in_sizes, int n_in,
                              void* d_out, int out_size, void* d_ws, size_t ws_size,
                              hipStream_t stream) {
    const float* x     = (const float*)d_in[0];
    const float* Wqkv  = (const float*)d_in[1];
    const float* bqkv  = (const float*)d_in[2];
    const float* Wproj = (const float*)d_in[3];
    const float* bproj = (const float*)d_in[4];
    float* out = (float*)d_out;

    char* ws = (char*)d_ws;
    ushort* xb   = (ushort*)(ws);                                  // 16 MB
    ushort* wqt  = (ushort*)(ws + (16u<<20));                      // 6 MB
    ushort* wpt  = (ushort*)(ws + (22u<<20));                      // 2 MB
    float*  cosT = (float*) (ws + (24u<<20));                      // 0.5 MB
    float*  sinT = (float*) (ws + (24u<<20) + (512u<<10));         // 0.5 MB
    ushort* qbuf = (ushort*)(ws + (25u<<20));                      // 16 MB (q pre-scaled, exp2 domain)
    ushort* kbuf = (ushort*)(ws + (41u<<20));                      // 16 MB
    ushort* vbuf = (ushort*)(ws + (57u<<20));                      // 16 MB (transposed [bh][D][S])
    ushort* obuf = (ushort*)(ws + (73u<<20));                      // 16 MB

    k_conv<<<(M_*KDIM/4 + 255)/256, 256, 0, stream>>>(x, xb, M_*KDIM/4);
    dim3 tb(32, 8);
    k_transpose<<<dim3(NQKV/32, KDIM/32), tb, 0, stream>>>(Wqkv, wqt, KDIM, NQKV);
    k_transpose<<<dim3(C_/32, KDIM/32), tb, 0, stream>>>(Wproj, wpt, KDIM, C_);
    k_rope_tab<<<(S_*D_ + 255)/256, 256, 0, stream>>>(cosT, sinT);

    k_qkv<<<768, 512, 0, stream>>>(xb, wqt, bqkv, cosT, sinT, qbuf, kbuf, vbuf);
    k_attn<<<dim3(B_*H_, S_/64), 256, 0, stream>>>(qbuf, kbuf, vbuf, obuf);
    k_proj<<<256, 512, 0, stream>>>(obuf, wpt, bproj, out);
}

// Round 8
// 190.369 us; speedup vs baseline: 3.3213x; 1.0572x over previous
//
#include <hip/hip_runtime.h>
#include <hip/hip_bf16.h>
#include <math.h>

#define B_ 4
#define S_ 2048
#define C_ 1024
#define H_ 16
#define D_ 64
#define M_ (B_*S_)      // 8192
#define NQKV (3*C_)     // 3072
#define KDIM C_         // 1024

typedef float f32x4 __attribute__((ext_vector_type(4)));
typedef float f32x16 __attribute__((ext_vector_type(16)));
typedef short bf16x8 __attribute__((ext_vector_type(8)));

static __device__ __forceinline__ ushort f2bf(float f){
    __hip_bfloat16 h = __float2bfloat16(f);
    union { __hip_bfloat16 b; ushort u; } v; v.b = h;
    return v.u;
}

// async global->LDS, 16B per lane; lds dest = wave-uniform base + lane*16 (linear)
static __device__ __forceinline__ void gload16(const ushort* g, ushort* l){
    __builtin_amdgcn_global_load_lds((__attribute__((address_space(1))) void*)g,
                                     (__attribute__((address_space(3))) void*)l,
                                     16, 0, 0);
}

// ---------------- convert x -> bf16 ----------------
__global__ void k_conv(const float* __restrict__ in, ushort* __restrict__ out, int n4){
    int i = blockIdx.x*blockDim.x + threadIdx.x;
    if (i < n4){
        float4 v = *(const float4*)(in + i*4);
        ushort4 o;
        o.x = f2bf(v.x); o.y = f2bf(v.y); o.z = f2bf(v.z); o.w = f2bf(v.w);
        *(ushort4*)(out + i*4) = o;
    }
}

// ---------------- transpose+convert W [R][Ccol] -> [Ccol][R] bf16 ----------------
__global__ void k_transpose(const float* __restrict__ in, ushort* __restrict__ out,
                            int R, int Ccol){
    __shared__ float tile[32][33];
    int c0 = blockIdx.x*32, r0 = blockIdx.y*32;
    int tx = threadIdx.x, ty = threadIdx.y;   // block (32,8)
    for (int j = ty; j < 32; j += 8)
        tile[j][tx] = in[(r0 + j)*Ccol + c0 + tx];
    __syncthreads();
    for (int j = ty; j < 32; j += 8)
        out[(size_t)(c0 + tx)*R + r0 + j] = f2bf(tile[j][tx]);
}

// ---------------- rope cos/sin tables [S][64] ----------------
__global__ void k_rope_tab(float* __restrict__ cosT, float* __restrict__ sinT){
    int t = blockIdx.x*blockDim.x + threadIdx.x;
    if (t >= S_*D_) return;
    int pos = t >> 6, j = t & 63;
    float invf = powf(10000.0f, -(float)(j & 31) / 32.0f);
    float ang = (float)pos * invf;
    cosT[t] = cosf(ang);
    sinT[t] = sinf(ang);
}

// ---------------- QKV GEMM (256x128 dbuf) + bias + RoPE + scatter; V transposed ----------------
// q output pre-scaled by 0.125*log2(e) so k_attn's softmax runs in exp2 domain.
__launch_bounds__(512, 4)
__global__ void k_qkv(const ushort* __restrict__ xb, const ushort* __restrict__ wt,
                      const float* __restrict__ bqkv,
                      const float* __restrict__ cosT, const float* __restrict__ sinT,
                      ushort* __restrict__ qb, ushort* __restrict__ kb, ushort* __restrict__ vT){
    __shared__ __align__(16) ushort As[2][256][32];
    __shared__ __align__(16) ushort Bs[2][128][32];
    int bid = blockIdx.x;                       // 768 blocks, XCD-grouped (A-panel-major)
    int lin = (bid & 7)*96 + (bid >> 3);
    int bx = lin % 24, by = lin / 24;
    int M0 = by*256, N0 = bx*128;
    int tid = threadIdx.x;
    int wid = tid >> 6, lane = tid & 63;
    int wm = wid >> 1, wn = wid & 1;
    int lrow = lane & 15, lk = lane >> 4;
    int swu = (lrow >> 1) & 3;                  // read-side XOR (row bits [2:1])

    int scol = (((lane & 3) ^ ((lane >> 3) & 3))) * 8;   // pre-swizzled source column
    const ushort* gA0 = &xb[(size_t)(M0 + wid*16 + (lane >> 2))*KDIM + scol];
    const ushort* gA1 = gA0 + (size_t)128*KDIM;
    const ushort* gB0 = &wt[(size_t)(N0 + wid*16 + (lane >> 2))*KDIM + scol];

    f32x4 acc[4][4] = {};
    int cur = 0;
    gload16(gA0, &As[0][wid*16][0]);
    gload16(gA1, &As[0][128 + wid*16][0]);
    gload16(gB0, &Bs[0][wid*16][0]);
    __syncthreads();

    for (int k0 = 0; k0 < KDIM; k0 += 32){
        int nk = k0 + 32;
        if (nk < KDIM){                          // prefetch next step into other buffer
            gload16(gA0 + nk, &As[cur^1][wid*16][0]);
            gload16(gA1 + nk, &As[cur^1][128 + wid*16][0]);
            gload16(gB0 + nk, &Bs[cur^1][wid*16][0]);
        }
        bf16x8 a[4], b[4];
#pragma unroll
        for (int mi = 0; mi < 4; mi++)
            a[mi] = *(const bf16x8*)(&As[cur][wm*64 + mi*16 + lrow][(lk ^ swu)*8]);
#pragma unroll
        for (int ni = 0; ni < 4; ni++)
            b[ni] = *(const bf16x8*)(&Bs[cur][wn*64 + ni*16 + lrow][(lk ^ swu)*8]);
#pragma unroll
        for (int mi = 0; mi < 4; mi++)
#pragma unroll
            for (int ni = 0; ni < 4; ni++)
                acc[mi][ni] = __builtin_amdgcn_mfma_f32_16x16x32_bf16(a[mi], b[ni], acc[mi][ni], 0, 0, 0);
        __syncthreads();
        cur ^= 1;
    }
#pragma unroll
    for (int mi = 0; mi < 4; mi++)
#pragma unroll
    for (int ni = 0; ni < 4; ni++){
        int gn = N0 + wn*64 + ni*16 + lrow;
        float bias = bqkv[gn];
        int which = gn >> 10;       // 0=q 1=k 2=v (uniform per block: 1024 % 128 == 0)
        int cn = gn & 1023;
        int h = cn >> 6, d = cn & 63;
        int gm0 = M0 + wm*64 + mi*16 + lk*4;
        if (which == 2){
            int bb = gm0 >> 11, pos0 = gm0 & 2047;
            ushort4 o = { f2bf(acc[mi][ni][0] + bias), f2bf(acc[mi][ni][1] + bias),
                          f2bf(acc[mi][ni][2] + bias), f2bf(acc[mi][ni][3] + bias) };
            *(ushort4*)(&vT[(((size_t)(bb*H_ + h))*D_ + d)*S_ + pos0]) = o;
        } else {
#pragma unroll
            for (int rr = 0; rr < 4; rr++){
                int gm = gm0 + rr;
                float val = acc[mi][ni][rr] + bias;
                float rot = __shfl_xor(val, 1);       // partner col (d^1), bias included
                int bb = gm >> 11, pos = gm & 2047;
                int out_idx = ((((bb*H_ + h)*S_) + pos))*D_ + d;
                float c = cosT[pos*64 + d], s = sinT[pos*64 + d];
                float o = val*c + ((d & 1) ? rot : -rot)*s;
                if (which == 0) o *= 0.18033688f;     // (1/sqrt(D)) * log2(e)
                ((which == 0) ? qb : kb)[out_idx] = f2bf(o);
            }
        }
    }
}

// ---------------- proj GEMM (256x128 dbuf) + bias -> fp32 out ----------------
__launch_bounds__(512, 4)
__global__ void k_proj(const ushort* __restrict__ ab, const ushort* __restrict__ wt,
                       const float* __restrict__ bias, float* __restrict__ out){
    __shared__ __align__(16) ushort As[2][256][32];
    __shared__ __align__(16) ushort Bs[2][128][32];
    int bid = blockIdx.x;                       // 256 blocks, XCD-grouped
    int lin = (bid & 7)*32 + (bid >> 3);
    int bx = lin & 7, by = lin >> 3;
    int M0 = by*256, N0 = bx*128;
    int tid = threadIdx.x;
    int wid = tid >> 6, lane = tid & 63;
    int wm = wid >> 1, wn = wid & 1;
    int lrow = lane & 15, lk = lane >> 4;
    int swu = (lrow >> 1) & 3;

    int scol = (((lane & 3) ^ ((lane >> 3) & 3))) * 8;
    const ushort* gA0 = &ab[(size_t)(M0 + wid*16 + (lane >> 2))*KDIM + scol];
    const ushort* gA1 = gA0 + (size_t)128*KDIM;
    const ushort* gB0 = &wt[(size_t)(N0 + wid*16 + (lane >> 2))*KDIM + scol];

    f32x4 acc[4][4] = {};
    int cur = 0;
    gload16(gA0, &As[0][wid*16][0]);
    gload16(gA1, &As[0][128 + wid*16][0]);
    gload16(gB0, &Bs[0][wid*16][0]);
    __syncthreads();

    for (int k0 = 0; k0 < KDIM; k0 += 32){
        int nk = k0 + 32;
        if (nk < KDIM){
            gload16(gA0 + nk, &As[cur^1][wid*16][0]);
            gload16(gA1 + nk, &As[cur^1][128 + wid*16][0]);
            gload16(gB0 + nk, &Bs[cur^1][wid*16][0]);
        }
        bf16x8 a[4], b[4];
#pragma unroll
        for (int mi = 0; mi < 4; mi++)
            a[mi] = *(const bf16x8*)(&As[cur][wm*64 + mi*16 + lrow][(lk ^ swu)*8]);
#pragma unroll
        for (int ni = 0; ni < 4; ni++)
            b[ni] = *(const bf16x8*)(&Bs[cur][wn*64 + ni*16 + lrow][(lk ^ swu)*8]);
#pragma unroll
        for (int mi = 0; mi < 4; mi++)
#pragma unroll
            for (int ni = 0; ni < 4; ni++)
                acc[mi][ni] = __builtin_amdgcn_mfma_f32_16x16x32_bf16(a[mi], b[ni], acc[mi][ni], 0, 0, 0);
        __syncthreads();
        cur ^= 1;
    }
#pragma unroll
    for (int mi = 0; mi < 4; mi++)
#pragma unroll
    for (int ni = 0; ni < 4; ni++){
        int gn = N0 + wn*64 + ni*16 + lrow;
        float bv = bias[gn];
#pragma unroll
        for (int rr = 0; rr < 4; rr++){
            int gm = M0 + wm*64 + mi*16 + lk*4 + rr;
            out[(size_t)gm*C_ + gn] = acc[mi][ni][rr] + bv;
        }
    }
}

// ---------------- causal flash attention: 32x32 MFMA, in-register P via cvt_pk+permlane ----
// grid = (bh, S/128), heavy-first.  4 waves x 32 q-rows = 128 q/block, KVBLK=64.
// Swapped QK^T: mfma(K,Q) -> col=lane&31=q, row=key=(reg&3)+8*(reg>>2)+4*(lane>>5).
__launch_bounds__(256, 3)
__global__ void k_attn(const ushort* __restrict__ qb, const ushort* __restrict__ kb,
                       const ushort* __restrict__ vT, ushort* __restrict__ ob){
    __shared__ __align__(16) ushort Ks[64][64];
    __shared__ __align__(16) ushort Vs[64][64];
    int bh = blockIdx.x;
    int qt = (gridDim.y - 1) - blockIdx.y;      // heavy blocks dispatch first
    int bb = bh >> 4, h = bh & 15;
    int tid = threadIdx.x, wid = tid >> 6, lane = tid & 63;
    int lq = lane & 31, hi = lane >> 5;
    const ushort* qp = qb + (size_t)bh*S_*D_;
    const ushort* kp = kb + (size_t)bh*S_*D_;
    const ushort* vp = vT + (size_t)bh*D_*S_;
    int qw = qt*128 + wid*32;
    int qrow = qw + lq;
    int swz = lq & 7;

    bf16x8 fq[4];                               // Q B-frags: k = c*16 + hi*8 + e
#pragma unroll
    for (int c = 0; c < 4; c++)
        fq[c] = *(const bf16x8*)(&qp[qrow*D_ + c*16 + hi*8]);

    f32x16 acc0 = {}, acc1 = {};                // O^T[d][q]: d = (reg&3)+8*(reg>>2)+4*hi (+32)
    float m = -1e30f, l = 0.0f;

    int tr = tid >> 3, tcu = tid & 7;
    int twu = (tcu ^ (tr & 7)) * 8;             // swizzled 16B-unit for stage writes
    int tc = tcu * 8;

    int4 ra = *(const int4*)(&kp[tr*D_ + tc]);
    int4 rb = *(const int4*)(&kp[(tr+32)*D_ + tc]);
    int4 rc = *(const int4*)(&vp[(size_t)tr*S_ + tc]);
    int4 rd = *(const int4*)(&vp[(size_t)(tr+32)*S_ + tc]);

    int nit = 2*qt + 2;
    for (int it = 0; it < nit; ++it){
        int j0 = it*64;
        *(int4*)(&Ks[tr][twu])    = ra;
        *(int4*)(&Ks[tr+32][twu]) = rb;
        *(int4*)(&Vs[tr][twu])    = rc;
        *(int4*)(&Vs[tr+32][twu]) = rd;
        __syncthreads();
        if (it + 1 < nit){
            int j1 = j0 + 64;                   // prefetch next tile; lands during compute
            ra = *(const int4*)(&kp[(j1+tr)*D_ + tc]);
            rb = *(const int4*)(&kp[(j1+tr+32)*D_ + tc]);
            rc = *(const int4*)(&vp[(size_t)tr*S_ + j1 + tc]);
            rd = *(const int4*)(&vp[(size_t)(tr+32)*S_ + j1 + tc]);
        }
        int rel = qw - j0;                      // wave-uniform; 32-aligned
        if (rel >= 0){
            bool diag0 = (rel == 0);
            bool have1 = (rel >= 32);
            bool diag1 = (rel == 32);
            f32x16 z0 = {}, z1 = {};
#pragma unroll
            for (int c = 0; c < 4; c++){
                bf16x8 kf = *(const bf16x8*)(&Ks[lq][((2*c + hi) ^ swz)*8]);
                z0 = __builtin_amdgcn_mfma_f32_32x32x16_bf16(kf, fq[c], z0, 0, 0, 0);
            }
            if (have1){
#pragma unroll
                for (int c = 0; c < 4; c++){
                    bf16x8 kf = *(const bf16x8*)(&Ks[32 + lq][((2*c + hi) ^ swz)*8]);
                    z1 = __builtin_amdgcn_mfma_f32_32x32x16_bf16(kf, fq[c], z1, 0, 0, 0);
                }
            }
            if (diag0){
#pragma unroll
                for (int r = 0; r < 16; r++)
                    if (((r & 3) + 8*(r >> 2) + 4*hi) > lq) z0[r] = -1e30f;
            }
            if (diag1){
#pragma unroll
                for (int r = 0; r < 16; r++)
                    if (((r & 3) + 8*(r >> 2) + 4*hi) > lq) z1[r] = -1e30f;
            }
            float tmax = z0[0];
#pragma unroll
            for (int r = 1; r < 16; r++) tmax = fmaxf(tmax, z0[r]);
            if (have1){
#pragma unroll
                for (int r = 0; r < 16; r++) tmax = fmaxf(tmax, z1[r]);
            }
            tmax = fmaxf(tmax, __shfl_xor(tmax, 32));
            if (__any(tmax > m)){               // skip rescale when running max unchanged
                float newm = fmaxf(m, tmax);
                float resc = exp2f(m - newm);
                m = newm; l *= resc;
#pragma unroll
                for (int r = 0; r < 16; r++){ acc0[r] *= resc; acc1[r] *= resc; }
            }
            float rsum = 0.0f;
#pragma unroll
            for (int r = 0; r < 16; r++){ z0[r] = exp2f(z0[r] - m); rsum += z0[r]; }
            if (have1){
#pragma unroll
                for (int r = 0; r < 16; r++){ z1[r] = exp2f(z1[r] - m); rsum += z1[r]; }
            }
            rsum += __shfl_xor(rsum, 32);
            l += rsum;

            // P->bf16 B-frags in-register: per 16-key sub, 4 cvt_pk + 2 permlane32_swap.
#define PV_SUB(zz, r0_, su, t) do {                                              \
    unsigned w0, w1, w2, w3;                                                     \
    asm("v_cvt_pk_bf16_f32 %0, %1, %2" : "=v"(w0) : "v"(zz[r0_+0]), "v"(zz[r0_+1])); \
    asm("v_cvt_pk_bf16_f32 %0, %1, %2" : "=v"(w1) : "v"(zz[r0_+2]), "v"(zz[r0_+3])); \
    asm("v_cvt_pk_bf16_f32 %0, %1, %2" : "=v"(w2) : "v"(zz[r0_+4]), "v"(zz[r0_+5])); \
    asm("v_cvt_pk_bf16_f32 %0, %1, %2" : "=v"(w3) : "v"(zz[r0_+6]), "v"(zz[r0_+7])); \
    auto s02 = __builtin_amdgcn_permlane32_swap(w0, w2, false, false);            \
    auto s13 = __builtin_amdgcn_permlane32_swap(w1, w3, false, false);            \
    union { unsigned u[4]; bf16x8 v; } pf;                                       \
    pf.u[0] = s02[0]; pf.u[1] = s13[0]; pf.u[2] = s02[1]; pf.u[3] = s13[1];      \
    bf16x8 vf0 = *(const bf16x8*)(&Vs[lq][(((su)*4 + (t)*2 + hi) ^ swz)*8]);     \
    acc0 = __builtin_amdgcn_mfma_f32_32x32x16_bf16(vf0, pf.v, acc0, 0, 0, 0);    \
    bf16x8 vf1 = *(const bf16x8*)(&Vs[32 + lq][(((su)*4 + (t)*2 + hi) ^ swz)*8]);\
    acc1 = __builtin_amdgcn_mfma_f32_32x32x16_bf16(vf1, pf.v, acc1, 0, 0, 0);    \
} while(0)

            PV_SUB(z0, 0, 0, 0);
            PV_SUB(z0, 8, 0, 1);
            if (have1){
                PV_SUB(z1, 0, 1, 0);
                PV_SUB(z1, 8, 1, 1);
            }
#undef PV_SUB
        }
        __syncthreads();
    }
    float rl = 1.0f / l;
#pragma unroll
    for (int rg = 0; rg < 4; rg++){
        ushort4 o0 = { f2bf(acc0[rg*4+0]*rl), f2bf(acc0[rg*4+1]*rl),
                       f2bf(acc0[rg*4+2]*rl), f2bf(acc0[rg*4+3]*rl) };
        *(ushort4*)(&ob[((size_t)(bb*S_ + qrow))*C_ + h*D_ + rg*8 + hi*4]) = o0;
        ushort4 o1 = { f2bf(acc1[rg*4+0]*rl), f2bf(acc1[rg*4+1]*rl),
                       f2bf(acc1[rg*4+2]*rl), f2bf(acc1[rg*4+3]*rl) };
        *(ushort4*)(&ob[((size_t)(bb*S_ + qrow))*C_ + h*D_ + 32 + rg*8 + hi*4]) = o1;
    }
}

extern "C" void kernel_launch(void* const* d_in, const int* in_sizes, int n_in,
                              void* d_out, int out_size, void* d_ws, size_t ws_size,
                              hipStream_t stream) {
    const float* x     = (const float*)d_in[0];
    const float* Wqkv  = (const float*)d_in[1];
    const float* bqkv  = (const float*)d_in[2];
    const float* Wproj = (const float*)d_in[3];
    const float* bproj = (const float*)d_in[4];
    float* out = (float*)d_out;

    char* ws = (char*)d_ws;
    ushort* xb   = (ushort*)(ws);                                  // 16 MB
    ushort* wqt  = (ushort*)(ws + (16u<<20));                      // 6 MB
    ushort* wpt  = (ushort*)(ws + (22u<<20));                      // 2 MB
    float*  cosT = (float*) (ws + (24u<<20));                      // 0.5 MB
    float*  sinT = (float*) (ws + (24u<<20) + (512u<<10));         // 0.5 MB
    ushort* qbuf = (ushort*)(ws + (25u<<20));                      // 16 MB (q pre-scaled, exp2 domain)
    ushort* kbuf = (ushort*)(ws + (41u<<20));                      // 16 MB
    ushort* vbuf = (ushort*)(ws + (57u<<20));                      // 16 MB (transposed [bh][D][S])
    ushort* obuf = (ushort*)(ws + (73u<<20));                      // 16 MB

    k_conv<<<(M_*KDIM/4 + 255)/256, 256, 0, stream>>>(x, xb, M_*KDIM/4);
    dim3 tb(32, 8);
    k_transpose<<<dim3(NQKV/32, KDIM/32), tb, 0, stream>>>(Wqkv, wqt, KDIM, NQKV);
    k_transpose<<<dim3(C_/32, KDIM/32), tb, 0, stream>>>(Wproj, wpt, KDIM, C_);
    k_rope_tab<<<(S_*D_ + 255)/256, 256, 0, stream>>>(cosT, sinT);

    k_qkv<<<768, 512, 0, stream>>>(xb, wqt, bqkv, cosT, sinT, qbuf, kbuf, vbuf);
    k_attn<<<dim3(B_*H_, S_/128), 256, 0, stream>>>(qbuf, kbuf, vbuf, obuf);
    k_proj<<<256, 512, 0, stream>>>(obuf, wpt, bproj, out);
}